// Round 1
// baseline (186.127 us; speedup 1.0000x reference)
//
#include <hip/hip_runtime.h>
#include <cstddef>

#define BATCH 64

// out[b,o,p] = bias[o] + sum_c in[b,c,p] * w[o,c]
// grid: (B, O/4), block: BLK threads over p
template<int C, int O, int P, int BLK>
__global__ void conv1x1_kernel(const float* __restrict__ in, const float* __restrict__ w,
                               const float* __restrict__ bias, float* __restrict__ out) {
  const int b  = blockIdx.x;
  const int o0 = blockIdx.y * 4;
  const float* __restrict__ inb = in + (size_t)b * C * P;
  const float* __restrict__ wr0 = w + (size_t)(o0 + 0) * C;
  const float* __restrict__ wr1 = w + (size_t)(o0 + 1) * C;
  const float* __restrict__ wr2 = w + (size_t)(o0 + 2) * C;
  const float* __restrict__ wr3 = w + (size_t)(o0 + 3) * C;
  const float b0 = bias[o0 + 0], b1 = bias[o0 + 1], b2 = bias[o0 + 2], b3 = bias[o0 + 3];
  for (int p = threadIdx.x; p < P; p += BLK) {
    float a0 = b0, a1 = b1, a2 = b2, a3 = b3;
#pragma unroll 8
    for (int c = 0; c < C; ++c) {
      float v = inb[c * P + p];
      a0 = fmaf(v, wr0[c], a0);
      a1 = fmaf(v, wr1[c], a1);
      a2 = fmaf(v, wr2[c], a2);
      a3 = fmaf(v, wr3[c], a3);
    }
    out[((size_t)b * O + (o0 + 0)) * P + p] = a0;
    out[((size_t)b * O + (o0 + 1)) * P + p] = a1;
    out[((size_t)b * O + (o0 + 2)) * P + p] = a2;
    out[((size_t)b * O + (o0 + 3)) * P + p] = a3;
  }
}

// 2x bilinear upsample (jax half-pixel, edge clamp). If PERM, the source
// channel is permuted per 28x28 output block: csrc = perms[i*64 + o],
// i = (y/28)*2 + (x/28). (Only used for H=28, C=64.)
template<int H, bool PERM>
__global__ void upsample2x_kernel(const float* __restrict__ src, float* __restrict__ dst,
                                  const int* __restrict__ perms, int C) {
  const int H2 = 2 * H;
  const long long total = (long long)BATCH * C * H2 * H2;
  for (long long idx = (long long)blockIdx.x * blockDim.x + threadIdx.x; idx < total;
       idx += (long long)gridDim.x * blockDim.x) {
    int x = (int)(idx % H2);
    long long t = idx / H2;
    int y = (int)(t % H2); t /= H2;
    int o = (int)(t % C);
    int b = (int)(t / C);
    int csrc = o;
    if (PERM) {
      int i = (y / 28) * 2 + (x / 28);
      csrc = perms[i * 64 + o];
    }
    const float* __restrict__ s = src + ((size_t)b * C + csrc) * (H * H);
    float fy = 0.5f * y - 0.25f;
    float fx = 0.5f * x - 0.25f;
    int y0 = (int)floorf(fy);
    int x0 = (int)floorf(fx);
    float wy = fy - (float)y0, wx = fx - (float)x0;
    int y0c = max(y0, 0), y1c = min(y0 + 1, H - 1);
    int x0c = max(x0, 0), x1c = min(x0 + 1, H - 1);
    float v00 = s[y0c * H + x0c], v01 = s[y0c * H + x1c];
    float v10 = s[y1c * H + x0c], v11 = s[y1c * H + x1c];
    float val = (1.f - wy) * ((1.f - wx) * v00 + wx * v01)
              +        wy  * ((1.f - wx) * v10 + wx * v11);
    dst[idx] = val;
  }
}

extern "C" void kernel_launch(void* const* d_in, const int* in_sizes, int n_in,
                              void* d_out, int out_size, void* d_ws, size_t ws_size,
                              hipStream_t stream) {
  const float* f1      = (const float*)d_in[0];
  const float* f2      = (const float*)d_in[1];
  const float* f3      = (const float*)d_in[2];
  const float* f4      = (const float*)d_in[3];
  const float* x_final = (const float*)d_in[4];
  const float* cw1     = (const float*)d_in[5];
  const float* cb1     = (const float*)d_in[6];
  const float* cw2     = (const float*)d_in[7];
  const float* cb2     = (const float*)d_in[8];
  const float* cw3     = (const float*)d_in[9];
  const float* cb3     = (const float*)d_in[10];
  const float* cw4     = (const float*)d_in[11];
  const float* cb4     = (const float*)d_in[12];
  const float* w1      = (const float*)d_in[13];
  const float* w2      = (const float*)d_in[14];
  const float* w3      = (const float*)d_in[15];
  const float* w4      = (const float*)d_in[16];
  const int*   perms   = (const int*)d_in[17];

  float* out = (float*)d_out;
  float* o_xfinal = out;                       // 64*512            = 32768
  float* o_aux1   = o_xfinal + 32768;          // 64*64*56*56       = 12845056
  float* o_aux2   = o_aux1 + 12845056;         // 64*128*28*28      = 6422528
  float* o_aux3   = o_aux2 + 6422528;          // 64*256*14*14      = 3211264
  float* o_aux4   = o_aux3 + 3211264;          // 64*512*7*7        = 1605632
  float* o_w1     = o_aux4 + 1605632;          // 64*56*56          = 200704
  float* o_w2     = o_w1 + 200704;             // 128*28*28         = 100352
  float* o_w3     = o_w2 + 100352;             // 256*14*14         = 50176
  float* o_w4     = o_w3 + 50176;              // 512*7*7           = 25088

  float* ws    = (float*)d_ws;
  float* conv1 = ws;                  // 64*64*784  = 3211264 floats
  float* conv2 = conv1 + 3211264;     // 64*128*196 = 1605632 floats
  float* conv3 = conv2 + 1605632;     // 64*256*49  =  802816 floats
  // total ws use: 5,619,712 floats = 22.5 MB

  // Pure copies
  hipMemcpyAsync(o_xfinal, x_final, (size_t)32768 * 4, hipMemcpyDeviceToDevice, stream);
  hipMemcpyAsync(o_w1, w1, (size_t)200704 * 4, hipMemcpyDeviceToDevice, stream);
  hipMemcpyAsync(o_w2, w2, (size_t)100352 * 4, hipMemcpyDeviceToDevice, stream);
  hipMemcpyAsync(o_w3, w3, (size_t)50176 * 4, hipMemcpyDeviceToDevice, stream);
  hipMemcpyAsync(o_w4, w4, (size_t)25088 * 4, hipMemcpyDeviceToDevice, stream);

  // 1x1 convs at LOW resolution (upsample commutes with 1x1 conv).
  // aux4: resize(7->7) is identity, so conv writes directly to output.
  conv1x1_kernel<64, 64, 784, 256><<<dim3(BATCH, 16), 256, 0, stream>>>(f1, cw1, cb1, conv1);
  conv1x1_kernel<128, 128, 196, 256><<<dim3(BATCH, 32), 256, 0, stream>>>(f2, cw2, cb2, conv2);
  conv1x1_kernel<128, 256, 49, 64><<<dim3(BATCH, 64), 64, 0, stream>>>(f3, cw3, cb3, conv3);
  conv1x1_kernel<512, 512, 49, 64><<<dim3(BATCH, 128), 64, 0, stream>>>(f4, cw4, cb4, o_aux4);

  // Bilinear 2x upsamples; aux1 fuses the per-block channel shuffle.
  upsample2x_kernel<28, true><<<2048, 256, 0, stream>>>(conv1, o_aux1, perms, 64);
  upsample2x_kernel<14, false><<<2048, 256, 0, stream>>>(conv2, o_aux2, nullptr, 128);
  upsample2x_kernel<7, false><<<2048, 256, 0, stream>>>(conv3, o_aux3, nullptr, 256);
}

// Round 2
// 182.104 us; speedup vs baseline: 1.0221x; 1.0221x over previous
//
#include <hip/hip_runtime.h>
#include <cstddef>

#define BATCH 64

__device__ __forceinline__ float4 ld4(const float* p) { return *(const float4*)p; }

// ---------------------------------------------------------------------------
// conv1x1 (64->64) at 28x28 + bilinear 2x upsample to 56x56 + per-quadrant
// channel permutation, fused. grid (B, 64/16), block 256 = 64 p-quads x 4 og.
// ---------------------------------------------------------------------------
__global__ void __launch_bounds__(256)
conv_up_perm1(const float* __restrict__ f, const float* __restrict__ w,
              const float* __restrict__ bias, const int* __restrict__ perms,
              float* __restrict__ out) {
  __shared__ float4 wT[64][4];   // [c][og] = {w[o0+og*4+k][c], k=0..3}
  __shared__ float ct[16][784];  // conv result tile [o_local][p]
  __shared__ float bs[16];
  __shared__ int inv[4][16];     // inverse perm: out channel for (quadrant, c_local)
  const int b = blockIdx.x, o0 = blockIdx.y * 16;
  const int tid = threadIdx.x;

  for (int i = tid; i < 64 * 4; i += 256) {
    int og = i / 64, c = i % 64;
    float4 t;
    t.x = w[(o0 + og * 4 + 0) * 64 + c];
    t.y = w[(o0 + og * 4 + 1) * 64 + c];
    t.z = w[(o0 + og * 4 + 2) * 64 + c];
    t.w = w[(o0 + og * 4 + 3) * 64 + c];
    wT[c][og] = t;
  }
  if (tid < 16) bs[tid] = bias[o0 + tid];
  if (tid >= 128 && tid < 192) {
    int t2 = tid - 128;
    int i = t2 >> 4, cl = t2 & 15;
    int c = o0 + cl;
    int r = 0;
    for (int j = 0; j < 64; ++j)
      if (perms[i * 64 + j] == c) r = j;
    inv[i][cl] = r;
  }
  __syncthreads();

  const float* __restrict__ inb = f + (size_t)b * 64 * 784;
  const int og = tid >> 6, pl = tid & 63;

  for (int q0 = 0; q0 < 196; q0 += 64) {
    int q = q0 + pl;
    if (q < 196) {
      int p0 = q * 4;
      float4 a0 = {0, 0, 0, 0}, a1 = a0, a2 = a0, a3 = a0;
#pragma unroll 4
      for (int c = 0; c < 64; ++c) {
        float4 v = ld4(inb + c * 784 + p0);
        float4 wv = wT[c][og];
        a0.x = fmaf(v.x, wv.x, a0.x); a0.y = fmaf(v.y, wv.x, a0.y);
        a0.z = fmaf(v.z, wv.x, a0.z); a0.w = fmaf(v.w, wv.x, a0.w);
        a1.x = fmaf(v.x, wv.y, a1.x); a1.y = fmaf(v.y, wv.y, a1.y);
        a1.z = fmaf(v.z, wv.y, a1.z); a1.w = fmaf(v.w, wv.y, a1.w);
        a2.x = fmaf(v.x, wv.z, a2.x); a2.y = fmaf(v.y, wv.z, a2.y);
        a2.z = fmaf(v.z, wv.z, a2.z); a2.w = fmaf(v.w, wv.z, a2.w);
        a3.x = fmaf(v.x, wv.w, a3.x); a3.y = fmaf(v.y, wv.w, a3.y);
        a3.z = fmaf(v.z, wv.w, a3.z); a3.w = fmaf(v.w, wv.w, a3.w);
      }
      float b0 = bs[og * 4 + 0], b1 = bs[og * 4 + 1], b2 = bs[og * 4 + 2], b3 = bs[og * 4 + 3];
      *(float4*)&ct[og * 4 + 0][p0] = make_float4(a0.x + b0, a0.y + b0, a0.z + b0, a0.w + b0);
      *(float4*)&ct[og * 4 + 1][p0] = make_float4(a1.x + b1, a1.y + b1, a1.z + b1, a1.w + b1);
      *(float4*)&ct[og * 4 + 2][p0] = make_float4(a2.x + b2, a2.y + b2, a2.z + b2, a2.w + b2);
      *(float4*)&ct[og * 4 + 3][p0] = make_float4(a3.x + b3, a3.y + b3, a3.z + b3, a3.w + b3);
    }
  }
  __syncthreads();

  // upsample 28->56 (half-pixel, edge clamp) + perm, write to global
  const size_t obase = (size_t)b * 64 * 3136;
  for (int cl = 0; cl < 16; ++cl) {
    const float* src = ct[cl];
    int j0 = inv[0][cl], j1 = inv[1][cl], j2 = inv[2][cl], j3 = inv[3][cl];
    for (int pix = tid; pix < 3136; pix += 256) {
      int y = pix / 56, x = pix - y * 56;
      int y0 = (y - 1) >> 1, x0 = (x - 1) >> 1;
      float wy = (y & 1) ? 0.25f : 0.75f;
      float wx = (x & 1) ? 0.25f : 0.75f;
      int y0c = y0 < 0 ? 0 : y0, y1c = y0 + 1 > 27 ? 27 : y0 + 1;
      int x0c = x0 < 0 ? 0 : x0, x1c = x0 + 1 > 27 ? 27 : x0 + 1;
      float t0 = src[y0c * 28 + x0c] * (1.f - wx) + src[y0c * 28 + x1c] * wx;
      float t1 = src[y1c * 28 + x0c] * (1.f - wx) + src[y1c * 28 + x1c] * wx;
      float val = t0 * (1.f - wy) + t1 * wy;
      int qi = ((y >= 28) ? 2 : 0) + ((x >= 28) ? 1 : 0);
      int j = (qi == 0) ? j0 : (qi == 1) ? j1 : (qi == 2) ? j2 : j3;
      out[obase + (size_t)j * 3136 + pix] = val;
    }
  }
}

// ---------------------------------------------------------------------------
// conv1x1 (C->O) at HxH + bilinear 2x upsample to 2Hx2H, fused.
// grid (B, O/16), block 256 = 64 p-lanes x 4 og.
// ---------------------------------------------------------------------------
template <int C, int O, int H, int VEC>
__global__ void __launch_bounds__(256)
conv_up_kernel(const float* __restrict__ f, const float* __restrict__ w,
               const float* __restrict__ bias, float* __restrict__ out) {
  constexpr int OT = 16;
  constexpr int P = H * H;
  constexpr int H2 = H * 2;
  constexpr int P2 = H2 * H2;
  __shared__ float4 wT[C][4];
  __shared__ float ct[OT][P];
  __shared__ float bs[OT];
  const int b = blockIdx.x, o0 = blockIdx.y * OT;
  const int tid = threadIdx.x;

  for (int i = tid; i < C * 4; i += 256) {
    int og = i / C, c = i % C;
    float4 t;
    t.x = w[(size_t)(o0 + og * 4 + 0) * C + c];
    t.y = w[(size_t)(o0 + og * 4 + 1) * C + c];
    t.z = w[(size_t)(o0 + og * 4 + 2) * C + c];
    t.w = w[(size_t)(o0 + og * 4 + 3) * C + c];
    wT[c][og] = t;
  }
  if (tid < OT) bs[tid] = bias[o0 + tid];
  __syncthreads();

  const float* __restrict__ inb = f + (size_t)b * C * P;
  const int og = tid >> 6, pl = tid & 63;

  if constexpr (VEC == 4) {
    for (int q0 = 0; q0 < P / 4; q0 += 64) {
      int q = q0 + pl;
      if (q < P / 4) {
        int p0 = q * 4;
        float4 a0 = {0, 0, 0, 0}, a1 = a0, a2 = a0, a3 = a0;
#pragma unroll 4
        for (int c = 0; c < C; ++c) {
          float4 v = ld4(inb + (size_t)c * P + p0);
          float4 wv = wT[c][og];
          a0.x = fmaf(v.x, wv.x, a0.x); a0.y = fmaf(v.y, wv.x, a0.y);
          a0.z = fmaf(v.z, wv.x, a0.z); a0.w = fmaf(v.w, wv.x, a0.w);
          a1.x = fmaf(v.x, wv.y, a1.x); a1.y = fmaf(v.y, wv.y, a1.y);
          a1.z = fmaf(v.z, wv.y, a1.z); a1.w = fmaf(v.w, wv.y, a1.w);
          a2.x = fmaf(v.x, wv.z, a2.x); a2.y = fmaf(v.y, wv.z, a2.y);
          a2.z = fmaf(v.z, wv.z, a2.z); a2.w = fmaf(v.w, wv.z, a2.w);
          a3.x = fmaf(v.x, wv.w, a3.x); a3.y = fmaf(v.y, wv.w, a3.y);
          a3.z = fmaf(v.z, wv.w, a3.z); a3.w = fmaf(v.w, wv.w, a3.w);
        }
        float b0 = bs[og * 4 + 0], b1 = bs[og * 4 + 1], b2 = bs[og * 4 + 2], b3 = bs[og * 4 + 3];
        *(float4*)&ct[og * 4 + 0][p0] = make_float4(a0.x + b0, a0.y + b0, a0.z + b0, a0.w + b0);
        *(float4*)&ct[og * 4 + 1][p0] = make_float4(a1.x + b1, a1.y + b1, a1.z + b1, a1.w + b1);
        *(float4*)&ct[og * 4 + 2][p0] = make_float4(a2.x + b2, a2.y + b2, a2.z + b2, a2.w + b2);
        *(float4*)&ct[og * 4 + 3][p0] = make_float4(a3.x + b3, a3.y + b3, a3.z + b3, a3.w + b3);
      }
    }
  } else {
    for (int p0 = 0; p0 < P; p0 += 64) {
      int p = p0 + pl;
      if (p < P) {
        float a0 = 0, a1 = 0, a2 = 0, a3 = 0;
#pragma unroll 4
        for (int c = 0; c < C; ++c) {
          float v = inb[(size_t)c * P + p];
          float4 wv = wT[c][og];
          a0 = fmaf(v, wv.x, a0);
          a1 = fmaf(v, wv.y, a1);
          a2 = fmaf(v, wv.z, a2);
          a3 = fmaf(v, wv.w, a3);
        }
        ct[og * 4 + 0][p] = a0 + bs[og * 4 + 0];
        ct[og * 4 + 1][p] = a1 + bs[og * 4 + 1];
        ct[og * 4 + 2][p] = a2 + bs[og * 4 + 2];
        ct[og * 4 + 3][p] = a3 + bs[og * 4 + 3];
      }
    }
  }
  __syncthreads();

  const size_t obase = (size_t)b * O * P2;
  for (int cl = 0; cl < OT; ++cl) {
    const float* src = ct[cl];
    float* dst = out + obase + (size_t)(o0 + cl) * P2;
    for (int pix = tid; pix < P2; pix += 256) {
      int y = pix / H2, x = pix - y * H2;
      int y0 = (y - 1) >> 1, x0 = (x - 1) >> 1;
      float wy = (y & 1) ? 0.25f : 0.75f;
      float wx = (x & 1) ? 0.25f : 0.75f;
      int y0c = y0 < 0 ? 0 : y0, y1c = y0 + 1 > H - 1 ? H - 1 : y0 + 1;
      int x0c = x0 < 0 ? 0 : x0, x1c = x0 + 1 > H - 1 ? H - 1 : x0 + 1;
      float t0 = src[y0c * H + x0c] * (1.f - wx) + src[y0c * H + x1c] * wx;
      float t1 = src[y1c * H + x0c] * (1.f - wx) + src[y1c * H + x1c] * wx;
      dst[pix] = t0 * (1.f - wy) + t1 * wy;
    }
  }
}

// ---------------------------------------------------------------------------
// conv4: 512->512 at 7x7, no upsample (7->7 resize is identity).
// grid (B, 512/32), block 256 = 32 p-lanes x 8 og; each thread: 2 pixels x 4 o.
// Weights staged in LDS in 128-c chunks.
// ---------------------------------------------------------------------------
__global__ void __launch_bounds__(256)
conv4_kernel(const float* __restrict__ f, const float* __restrict__ w,
             const float* __restrict__ bias, float* __restrict__ out) {
  __shared__ float4 wT[128][8];  // [c within chunk][og]
  const int b = blockIdx.x, o0 = blockIdx.y * 32;
  const int tid = threadIdx.x;
  const int og = tid >> 5, pl = tid & 31;
  const float* __restrict__ inb = f + (size_t)b * 512 * 49;

  float a00 = 0, a01 = 0, a10 = 0, a11 = 0, a20 = 0, a21 = 0, a30 = 0, a31 = 0;

  for (int cc = 0; cc < 512; cc += 128) {
    __syncthreads();
    for (int i = tid; i < 128 * 8; i += 256) {
      int g = i / 128, c = i % 128;
      float4 t;
      t.x = w[(size_t)(o0 + g * 4 + 0) * 512 + cc + c];
      t.y = w[(size_t)(o0 + g * 4 + 1) * 512 + cc + c];
      t.z = w[(size_t)(o0 + g * 4 + 2) * 512 + cc + c];
      t.w = w[(size_t)(o0 + g * 4 + 3) * 512 + cc + c];
      wT[c][g] = t;
    }
    __syncthreads();
#pragma unroll 4
    for (int c = 0; c < 128; ++c) {
      float v0 = inb[(size_t)(cc + c) * 49 + pl];
      float v1 = (pl < 17) ? inb[(size_t)(cc + c) * 49 + pl + 32] : 0.f;
      float4 wv = wT[c][og];
      a00 = fmaf(v0, wv.x, a00); a01 = fmaf(v1, wv.x, a01);
      a10 = fmaf(v0, wv.y, a10); a11 = fmaf(v1, wv.y, a11);
      a20 = fmaf(v0, wv.z, a20); a21 = fmaf(v1, wv.z, a21);
      a30 = fmaf(v0, wv.w, a30); a31 = fmaf(v1, wv.w, a31);
    }
  }

  float r0[4] = {a00, a10, a20, a30};
  float r1[4] = {a01, a11, a21, a31};
#pragma unroll
  for (int i = 0; i < 4; ++i) {
    int o = o0 + og * 4 + i;
    float bv = bias[o];
    out[((size_t)b * 512 + o) * 49 + pl] = r0[i] + bv;
    if (pl < 17) out[((size_t)b * 512 + o) * 49 + pl + 32] = r1[i] + bv;
  }
}

extern "C" void kernel_launch(void* const* d_in, const int* in_sizes, int n_in,
                              void* d_out, int out_size, void* d_ws, size_t ws_size,
                              hipStream_t stream) {
  const float* f1      = (const float*)d_in[0];
  const float* f2      = (const float*)d_in[1];
  const float* f3      = (const float*)d_in[2];
  const float* f4      = (const float*)d_in[3];
  const float* x_final = (const float*)d_in[4];
  const float* cw1     = (const float*)d_in[5];
  const float* cb1     = (const float*)d_in[6];
  const float* cw2     = (const float*)d_in[7];
  const float* cb2     = (const float*)d_in[8];
  const float* cw3     = (const float*)d_in[9];
  const float* cb3     = (const float*)d_in[10];
  const float* cw4     = (const float*)d_in[11];
  const float* cb4     = (const float*)d_in[12];
  const float* w1      = (const float*)d_in[13];
  const float* w2      = (const float*)d_in[14];
  const float* w3      = (const float*)d_in[15];
  const float* w4      = (const float*)d_in[16];
  const int*   perms   = (const int*)d_in[17];

  float* out = (float*)d_out;
  float* o_xfinal = out;                       // 64*512            = 32768
  float* o_aux1   = o_xfinal + 32768;          // 64*64*56*56       = 12845056
  float* o_aux2   = o_aux1 + 12845056;         // 64*128*28*28      = 6422528
  float* o_aux3   = o_aux2 + 6422528;          // 64*256*14*14      = 3211264
  float* o_aux4   = o_aux3 + 3211264;          // 64*512*7*7        = 1605632
  float* o_w1     = o_aux4 + 1605632;          // 64*56*56          = 200704
  float* o_w2     = o_w1 + 200704;             // 128*28*28         = 100352
  float* o_w3     = o_w2 + 100352;             // 256*14*14         = 50176
  float* o_w4     = o_w3 + 50176;              // 512*7*7           = 25088

  hipMemcpyAsync(o_xfinal, x_final, (size_t)32768 * 4, hipMemcpyDeviceToDevice, stream);
  hipMemcpyAsync(o_w1, w1, (size_t)200704 * 4, hipMemcpyDeviceToDevice, stream);
  hipMemcpyAsync(o_w2, w2, (size_t)100352 * 4, hipMemcpyDeviceToDevice, stream);
  hipMemcpyAsync(o_w3, w3, (size_t)50176 * 4, hipMemcpyDeviceToDevice, stream);
  hipMemcpyAsync(o_w4, w4, (size_t)25088 * 4, hipMemcpyDeviceToDevice, stream);

  conv_up_perm1<<<dim3(BATCH, 4), 256, 0, stream>>>(f1, cw1, cb1, perms, o_aux1);
  conv_up_kernel<128, 128, 14, 4><<<dim3(BATCH, 8), 256, 0, stream>>>(f2, cw2, cb2, o_aux2);
  conv_up_kernel<128, 256, 7, 1><<<dim3(BATCH, 16), 256, 0, stream>>>(f3, cw3, cb3, o_aux3);
  conv4_kernel<<<dim3(BATCH, 16), 256, 0, stream>>>(f4, cw4, cb4, o_aux4);
}

// Round 4
// 103.470 us; speedup vs baseline: 1.7988x; 1.7600x over previous
//
#include <hip/hip_runtime.h>
#include <hip/hip_bf16.h>
#include <cstddef>

#define BATCH 64

typedef __attribute__((ext_vector_type(8))) short bf16x8;
typedef __attribute__((ext_vector_type(4))) float f32x4;

__device__ __forceinline__ float4 ld4(const float* p) { return *(const float4*)p; }
__device__ __forceinline__ unsigned short f2bf(float v) {
  __hip_bfloat16 h = __float2bfloat16(v);
  return *(unsigned short*)&h;
}

// 2x bilinear upsample of one 2x2 output quad from a HxH src row-major tile.
// dst points at output pixel (2qy, 2qx); pitch = output row stride (2H).
template <int H>
__device__ __forceinline__ void upsample_quad(const float* __restrict__ src, int qy, int qx,
                                              float* __restrict__ dst, int pitch) {
  int rm = qy > 0 ? qy - 1 : 0, rp = qy < H - 1 ? qy + 1 : H - 1;
  int cm = qx > 0 ? qx - 1 : 0, cp = qx < H - 1 ? qx + 1 : H - 1;
  const float* s0 = src + rm * H;
  const float* s1 = src + qy * H;
  const float* s2 = src + rp * H;
  float tA0 = 0.25f * s0[cm] + 0.75f * s0[qx], tA1 = 0.75f * s0[qx] + 0.25f * s0[cp];
  float tB0 = 0.25f * s1[cm] + 0.75f * s1[qx], tB1 = 0.75f * s1[qx] + 0.25f * s1[cp];
  float tC0 = 0.25f * s2[cm] + 0.75f * s2[qx], tC1 = 0.75f * s2[qx] + 0.25f * s2[cp];
  float2 r0 = make_float2(0.25f * tA0 + 0.75f * tB0, 0.25f * tA1 + 0.75f * tB1);
  float2 r1 = make_float2(0.75f * tB0 + 0.25f * tC0, 0.75f * tB1 + 0.25f * tC1);
  *(float2*)dst = r0;
  *(float2*)(dst + pitch) = r1;
}

// ---------------------------------------------------------------------------
// misc: 5 output copies (fp32) + w4 -> bf16 conversion, fused. grid-stride.
// ---------------------------------------------------------------------------
__global__ void misc_kernel(const float* __restrict__ cw4, unsigned short* __restrict__ w4b,
                            const float* __restrict__ xf, const float* __restrict__ w1,
                            const float* __restrict__ w2, const float* __restrict__ w3,
                            const float* __restrict__ w4s, float* __restrict__ out) {
  int idx = blockIdx.x * blockDim.x + threadIdx.x;
  int stride = gridDim.x * blockDim.x;
  for (int i = idx; i < 65536; i += stride) {  // 512*512/4
    float4 v = ld4(cw4 + 4 * i);
    ushort4 u;
    u.x = f2bf(v.x); u.y = f2bf(v.y); u.z = f2bf(v.z); u.w = f2bf(v.w);
    *(ushort4*)(w4b + 4 * i) = u;
  }
  float4* o4 = (float4*)out;
  const size_t W1 = 24117248u / 4;  // o_w1 offset in float4s
  for (int i = idx; i < 8192; i += stride) o4[i] = ((const float4*)xf)[i];
  for (int i = idx; i < 50176; i += stride) o4[W1 + i] = ((const float4*)w1)[i];
  for (int i = idx; i < 25088; i += stride) o4[W1 + 50176 + i] = ((const float4*)w2)[i];
  for (int i = idx; i < 12544; i += stride) o4[W1 + 75264 + i] = ((const float4*)w3)[i];
  for (int i = idx; i < 6272; i += stride) o4[W1 + 87808 + i] = ((const float4*)w4s)[i];
}

// ---------------------------------------------------------------------------
// prep_inT: f4[b][c][p(49)] fp32 -> inT[b][p(64,pad0)][c] bf16 (transposed).
// grid (64, 4): (batch, 128-channel chunk). block 256.
// ---------------------------------------------------------------------------
__global__ void __launch_bounds__(256)
prep_inT(const float* __restrict__ f4, unsigned short* __restrict__ inT) {
  __shared__ unsigned short tile[128][50];
  const int b = blockIdx.x, c0 = blockIdx.y * 128;
  const float* src = f4 + ((size_t)b * 512 + c0) * 49;
  for (int i = threadIdx.x; i < 128 * 49; i += 256) {
    int ci = i / 49, p = i - ci * 49;
    tile[ci][p] = f2bf(src[i]);
  }
  __syncthreads();
  unsigned short* dst = inT + (size_t)b * 64 * 512 + c0;
  for (int i = threadIdx.x; i < 64 * 128; i += 256) {
    int p = i >> 7, ci = i & 127;
    dst[(size_t)p * 512 + ci] = (p < 49) ? tile[ci][p] : (unsigned short)0;
  }
}

// ---------------------------------------------------------------------------
// conv4 as bf16 MFMA GEMM: out[b,o,p] = bias[o] + sum_c w[o,c] in[b,c,p].
// A = w4b (512x512, row-major over c), B = inT[b] (64 cols padded, c-major).
// grid (64, 4): (batch, 128-row m-block). 4 waves; wave = 32 rows x 64 cols.
// No LDS: frags loaded straight from L2-resident global.
// ---------------------------------------------------------------------------
__global__ void __launch_bounds__(256)
conv4_mfma(const unsigned short* __restrict__ w4b, const unsigned short* __restrict__ inT,
           const float* __restrict__ bias, float* __restrict__ out) {
  const int b = blockIdx.x;
  const int wm = blockIdx.y * 128 + (threadIdx.x >> 6) * 32;
  const int lane = threadIdx.x & 63;
  const int l15 = lane & 15, lg = lane >> 4;

  f32x4 acc[2][4];
  for (int m = 0; m < 2; ++m) {
    float bv0 = bias[wm + m * 16 + lg * 4 + 0];
    float bv1 = bias[wm + m * 16 + lg * 4 + 1];
    float bv2 = bias[wm + m * 16 + lg * 4 + 2];
    float bv3 = bias[wm + m * 16 + lg * 4 + 3];
    for (int n = 0; n < 4; ++n) {
      acc[m][n][0] = bv0; acc[m][n][1] = bv1; acc[m][n][2] = bv2; acc[m][n][3] = bv3;
    }
  }

  const unsigned short* a0p = w4b + (size_t)(wm + l15) * 512 + lg * 8;
  const unsigned short* a1p = a0p + 16 * 512;
  const unsigned short* bp = inT + (size_t)b * 64 * 512 + (size_t)l15 * 512 + lg * 8;

#pragma unroll 4
  for (int k0 = 0; k0 < 512; k0 += 32) {
    bf16x8 A0 = *(const bf16x8*)(a0p + k0);
    bf16x8 A1 = *(const bf16x8*)(a1p + k0);
    bf16x8 B0 = *(const bf16x8*)(bp + k0);
    bf16x8 B1 = *(const bf16x8*)(bp + 16 * 512 + k0);
    bf16x8 B2 = *(const bf16x8*)(bp + 32 * 512 + k0);
    bf16x8 B3 = *(const bf16x8*)(bp + 48 * 512 + k0);
    acc[0][0] = __builtin_amdgcn_mfma_f32_16x16x32_bf16(A0, B0, acc[0][0], 0, 0, 0);
    acc[0][1] = __builtin_amdgcn_mfma_f32_16x16x32_bf16(A0, B1, acc[0][1], 0, 0, 0);
    acc[0][2] = __builtin_amdgcn_mfma_f32_16x16x32_bf16(A0, B2, acc[0][2], 0, 0, 0);
    acc[0][3] = __builtin_amdgcn_mfma_f32_16x16x32_bf16(A0, B3, acc[0][3], 0, 0, 0);
    acc[1][0] = __builtin_amdgcn_mfma_f32_16x16x32_bf16(A1, B0, acc[1][0], 0, 0, 0);
    acc[1][1] = __builtin_amdgcn_mfma_f32_16x16x32_bf16(A1, B1, acc[1][1], 0, 0, 0);
    acc[1][2] = __builtin_amdgcn_mfma_f32_16x16x32_bf16(A1, B2, acc[1][2], 0, 0, 0);
    acc[1][3] = __builtin_amdgcn_mfma_f32_16x16x32_bf16(A1, B3, acc[1][3], 0, 0, 0);
  }

  float* outb = out + (size_t)b * 512 * 49;
#pragma unroll
  for (int m = 0; m < 2; ++m)
#pragma unroll
    for (int n = 0; n < 4; ++n) {
      int p = n * 16 + l15;
      if (p < 49) {
#pragma unroll
        for (int r = 0; r < 4; ++r) {
          int o = wm + m * 16 + lg * 4 + r;
          outb[(size_t)o * 49 + p] = acc[m][n][r];
        }
      }
    }
}

// ---------------------------------------------------------------------------
// conv1 (64->64 @28x28) + 2x upsample to 56x56 + per-quadrant perm, fused.
// grid (64, 4), block 256. 16 out-ch per wg.
// ---------------------------------------------------------------------------
__global__ void __launch_bounds__(256)
conv_up_perm1(const float* __restrict__ f, const float* __restrict__ w,
              const float* __restrict__ bias, const int* __restrict__ perms,
              float* __restrict__ out) {
  __shared__ float4 wT[64][4];
  __shared__ float ct[16][784];
  __shared__ float bs[16];
  __shared__ int inv[4][16];
  const int b = blockIdx.x, o0 = blockIdx.y * 16;
  const int tid = threadIdx.x;

  {
    int og = tid >> 6, c = tid & 63;  // exactly 256 = 4*64
    float4 t;
    t.x = w[(o0 + og * 4 + 0) * 64 + c];
    t.y = w[(o0 + og * 4 + 1) * 64 + c];
    t.z = w[(o0 + og * 4 + 2) * 64 + c];
    t.w = w[(o0 + og * 4 + 3) * 64 + c];
    wT[c][og] = t;
  }
  if (tid < 16) bs[tid] = bias[o0 + tid];
  if (tid >= 128 && tid < 192) {
    int t2 = tid - 128;
    int i = t2 >> 4, cl = t2 & 15;
    int c = o0 + cl;
    int r = 0;
    for (int j = 0; j < 64; ++j)
      if (perms[i * 64 + j] == c) r = j;
    inv[i][cl] = r;
  }
  __syncthreads();

  const float* __restrict__ inb = f + (size_t)b * 64 * 784;
  const int og = tid >> 6, pl = tid & 63;

  for (int q0 = 0; q0 < 196; q0 += 64) {
    int q = q0 + pl;
    if (q < 196) {
      int p0 = q * 4;
      float4 a0 = {0, 0, 0, 0}, a1 = a0, a2 = a0, a3 = a0;
#pragma unroll 4
      for (int c = 0; c < 64; ++c) {
        float4 v = ld4(inb + c * 784 + p0);
        float4 wv = wT[c][og];
        a0.x = fmaf(v.x, wv.x, a0.x); a0.y = fmaf(v.y, wv.x, a0.y);
        a0.z = fmaf(v.z, wv.x, a0.z); a0.w = fmaf(v.w, wv.x, a0.w);
        a1.x = fmaf(v.x, wv.y, a1.x); a1.y = fmaf(v.y, wv.y, a1.y);
        a1.z = fmaf(v.z, wv.y, a1.z); a1.w = fmaf(v.w, wv.y, a1.w);
        a2.x = fmaf(v.x, wv.z, a2.x); a2.y = fmaf(v.y, wv.z, a2.y);
        a2.z = fmaf(v.z, wv.z, a2.z); a2.w = fmaf(v.w, wv.z, a2.w);
        a3.x = fmaf(v.x, wv.w, a3.x); a3.y = fmaf(v.y, wv.w, a3.y);
        a3.z = fmaf(v.z, wv.w, a3.z); a3.w = fmaf(v.w, wv.w, a3.w);
      }
      float b0 = bs[og * 4 + 0], b1 = bs[og * 4 + 1], b2 = bs[og * 4 + 2], b3 = bs[og * 4 + 3];
      *(float4*)&ct[og * 4 + 0][p0] = make_float4(a0.x + b0, a0.y + b0, a0.z + b0, a0.w + b0);
      *(float4*)&ct[og * 4 + 1][p0] = make_float4(a1.x + b1, a1.y + b1, a1.z + b1, a1.w + b1);
      *(float4*)&ct[og * 4 + 2][p0] = make_float4(a2.x + b2, a2.y + b2, a2.z + b2, a2.w + b2);
      *(float4*)&ct[og * 4 + 3][p0] = make_float4(a3.x + b3, a3.y + b3, a3.z + b3, a3.w + b3);
    }
  }
  __syncthreads();

  // quad-based upsample + perm: 16 ch x 28x28 quads
  const size_t obase = (size_t)b * 64 * 3136;
  for (int i = tid; i < 16 * 784; i += 256) {
    int cl = i / 784;
    int q = i - cl * 784;
    int qy = q / 28, qx = q - qy * 28;
    int qi = ((qy >= 14) ? 2 : 0) + ((qx >= 14) ? 1 : 0);
    int j = inv[qi][cl];
    float* dst = out + obase + (size_t)j * 3136 + (size_t)(2 * qy) * 56 + 2 * qx;
    upsample_quad<28>(ct[cl], qy, qx, dst, 56);
  }
}

// ---------------------------------------------------------------------------
// conv2 (128->128 @14x14) + 2x upsample to 28x28. grid (64,4), block 512.
// 32 out-ch per wg.
// ---------------------------------------------------------------------------
__global__ void __launch_bounds__(512)
conv_up2(const float* __restrict__ f, const float* __restrict__ w,
         const float* __restrict__ bias, float* __restrict__ out) {
  __shared__ float4 wT[128][8];
  __shared__ float ct[32][196];
  __shared__ float bs[32];
  const int b = blockIdx.x, o0 = blockIdx.y * 32;
  const int tid = threadIdx.x;

  for (int i = tid; i < 1024; i += 512) {
    int og = i >> 7, c = i & 127;
    float4 t;
    t.x = w[(size_t)(o0 + og * 4 + 0) * 128 + c];
    t.y = w[(size_t)(o0 + og * 4 + 1) * 128 + c];
    t.z = w[(size_t)(o0 + og * 4 + 2) * 128 + c];
    t.w = w[(size_t)(o0 + og * 4 + 3) * 128 + c];
    wT[c][og] = t;
  }
  if (tid < 32) bs[tid] = bias[o0 + tid];
  __syncthreads();

  const float* __restrict__ inb = f + (size_t)b * 128 * 196;
  const int og = tid >> 6, pl = tid & 63;  // og 0..7

  if (pl < 49) {
    int p0 = pl * 4;
    float4 a0 = {0, 0, 0, 0}, a1 = a0, a2 = a0, a3 = a0;
#pragma unroll 4
    for (int c = 0; c < 128; ++c) {
      float4 v = ld4(inb + c * 196 + p0);
      float4 wv = wT[c][og];
      a0.x = fmaf(v.x, wv.x, a0.x); a0.y = fmaf(v.y, wv.x, a0.y);
      a0.z = fmaf(v.z, wv.x, a0.z); a0.w = fmaf(v.w, wv.x, a0.w);
      a1.x = fmaf(v.x, wv.y, a1.x); a1.y = fmaf(v.y, wv.y, a1.y);
      a1.z = fmaf(v.z, wv.y, a1.z); a1.w = fmaf(v.w, wv.y, a1.w);
      a2.x = fmaf(v.x, wv.z, a2.x); a2.y = fmaf(v.y, wv.z, a2.y);
      a2.z = fmaf(v.z, wv.z, a2.z); a2.w = fmaf(v.w, wv.z, a2.w);
      a3.x = fmaf(v.x, wv.w, a3.x); a3.y = fmaf(v.y, wv.w, a3.y);
      a3.z = fmaf(v.z, wv.w, a3.z); a3.w = fmaf(v.w, wv.w, a3.w);
    }
    float b0 = bs[og * 4 + 0], b1 = bs[og * 4 + 1], b2 = bs[og * 4 + 2], b3 = bs[og * 4 + 3];
    *(float4*)&ct[og * 4 + 0][p0] = make_float4(a0.x + b0, a0.y + b0, a0.z + b0, a0.w + b0);
    *(float4*)&ct[og * 4 + 1][p0] = make_float4(a1.x + b1, a1.y + b1, a1.z + b1, a1.w + b1);
    *(float4*)&ct[og * 4 + 2][p0] = make_float4(a2.x + b2, a2.y + b2, a2.z + b2, a2.w + b2);
    *(float4*)&ct[og * 4 + 3][p0] = make_float4(a3.x + b3, a3.y + b3, a3.z + b3, a3.w + b3);
  }
  __syncthreads();

  // FIXED: 14x14 source tile -> 196 quads per channel (was 49 / H=7 indexing)
  const size_t obase = (size_t)b * 128 * 784;
  for (int i = tid; i < 32 * 196; i += 512) {
    int cl = i / 196;
    int q = i - cl * 196;
    int qy = q / 14, qx = q - qy * 14;
    float* dst = out + obase + (size_t)(o0 + cl) * 784 + (size_t)(2 * qy) * 28 + 2 * qx;
    upsample_quad<14>(ct[cl], qy, qx, dst, 28);
  }
}

// ---------------------------------------------------------------------------
// conv3 (128->256 @7x7) + 2x upsample to 14x14. grid (64,8), block 256.
// 32 out-ch per wg; og handles 8 och.
// ---------------------------------------------------------------------------
__global__ void __launch_bounds__(256)
conv_up3(const float* __restrict__ f, const float* __restrict__ w,
         const float* __restrict__ bias, float* __restrict__ out) {
  __shared__ float wT[128][32];
  __shared__ float ct[32][49];
  __shared__ float bs[32];
  const int b = blockIdx.x, o0 = blockIdx.y * 32;
  const int tid = threadIdx.x;

  for (int i = tid; i < 4096; i += 256) {
    int c = i >> 5, ol = i & 31;
    wT[c][ol] = w[(size_t)(o0 + ol) * 128 + c];
  }
  if (tid < 32) bs[tid] = bias[o0 + tid];
  __syncthreads();

  const float* __restrict__ inb = f + (size_t)b * 128 * 49;
  const int og = tid >> 6, pl = tid & 63;

  if (pl < 49) {
    float a[8] = {0, 0, 0, 0, 0, 0, 0, 0};
#pragma unroll 4
    for (int c = 0; c < 128; ++c) {
      float v = inb[c * 49 + pl];
      float4 wa = *(float4*)&wT[c][og * 8];
      float4 wb = *(float4*)&wT[c][og * 8 + 4];
      a[0] = fmaf(v, wa.x, a[0]); a[1] = fmaf(v, wa.y, a[1]);
      a[2] = fmaf(v, wa.z, a[2]); a[3] = fmaf(v, wa.w, a[3]);
      a[4] = fmaf(v, wb.x, a[4]); a[5] = fmaf(v, wb.y, a[5]);
      a[6] = fmaf(v, wb.z, a[6]); a[7] = fmaf(v, wb.w, a[7]);
    }
#pragma unroll
    for (int k = 0; k < 8; ++k) ct[og * 8 + k][pl] = a[k] + bs[og * 8 + k];
  }
  __syncthreads();

  const size_t obase = (size_t)b * 256 * 196;
  for (int i = tid; i < 32 * 49; i += 256) {
    int cl = i / 49;
    int q = i - cl * 49;
    int qy = q / 7, qx = q - qy * 7;
    float* dst = out + obase + (size_t)(o0 + cl) * 196 + (size_t)(2 * qy) * 14 + 2 * qx;
    upsample_quad<7>(ct[cl], qy, qx, dst, 14);
  }
}

extern "C" void kernel_launch(void* const* d_in, const int* in_sizes, int n_in,
                              void* d_out, int out_size, void* d_ws, size_t ws_size,
                              hipStream_t stream) {
  const float* f1      = (const float*)d_in[0];
  const float* f2      = (const float*)d_in[1];
  const float* f3      = (const float*)d_in[2];
  const float* f4      = (const float*)d_in[3];
  const float* x_final = (const float*)d_in[4];
  const float* cw1     = (const float*)d_in[5];
  const float* cb1     = (const float*)d_in[6];
  const float* cw2     = (const float*)d_in[7];
  const float* cb2     = (const float*)d_in[8];
  const float* cw3     = (const float*)d_in[9];
  const float* cb3     = (const float*)d_in[10];
  const float* cw4     = (const float*)d_in[11];
  const float* cb4     = (const float*)d_in[12];
  const float* w1      = (const float*)d_in[13];
  const float* w2      = (const float*)d_in[14];
  const float* w3      = (const float*)d_in[15];
  const float* w4      = (const float*)d_in[16];
  const int*   perms   = (const int*)d_in[17];

  float* out = (float*)d_out;
  float* o_aux1 = out + 32768;
  float* o_aux2 = o_aux1 + 12845056;
  float* o_aux3 = o_aux2 + 6422528;
  float* o_aux4 = o_aux3 + 3211264;

  unsigned short* inT = (unsigned short*)d_ws;           // 64*64*512 bf16 = 4 MB
  unsigned short* w4b = inT + (size_t)64 * 64 * 512;     // 512*512 bf16 = 0.5 MB

  misc_kernel<<<512, 256, 0, stream>>>(cw4, w4b, x_final, w1, w2, w3, w4, out);
  prep_inT<<<dim3(BATCH, 4), 256, 0, stream>>>(f4, inT);
  conv_up_perm1<<<dim3(BATCH, 4), 256, 0, stream>>>(f1, cw1, cb1, perms, o_aux1);
  conv4_mfma<<<dim3(BATCH, 4), 256, 0, stream>>>(w4b, inT, cb4, o_aux4);
  conv_up2<<<dim3(BATCH, 4), 512, 0, stream>>>(f2, cw2, cb2, o_aux2);
  conv_up3<<<dim3(BATCH, 8), 256, 0, stream>>>(f3, cw3, cb3, o_aux3);
}

// Round 5
// 95.207 us; speedup vs baseline: 1.9550x; 1.0868x over previous
//
#include <hip/hip_runtime.h>
#include <hip/hip_bf16.h>
#include <cstddef>

#define BATCH 64

typedef __attribute__((ext_vector_type(8))) short bf16x8;
typedef __attribute__((ext_vector_type(4))) float f32x4;

__device__ __forceinline__ float4 ld4(const float* p) { return *(const float4*)p; }
__device__ __forceinline__ float2 ld2(const float* p) { return *(const float2*)p; }
__device__ __forceinline__ unsigned short f2bf(float v) {
  __hip_bfloat16 h = __float2bfloat16(v);
  return *(unsigned short*)&h;
}

// 2x bilinear upsample of one 2x2 quad given the three source rows
// (top/center/bottom already halo-resolved); only column clamp applied here.
__device__ __forceinline__ void up_quad_rows(const float* __restrict__ s0,
                                             const float* __restrict__ s1,
                                             const float* __restrict__ s2,
                                             int qx, int W, float* __restrict__ dst, int pitch) {
  int cm = qx > 0 ? qx - 1 : 0, cp = qx < W - 1 ? qx + 1 : W - 1;
  float tA0 = 0.25f * s0[cm] + 0.75f * s0[qx], tA1 = 0.75f * s0[qx] + 0.25f * s0[cp];
  float tB0 = 0.25f * s1[cm] + 0.75f * s1[qx], tB1 = 0.75f * s1[qx] + 0.25f * s1[cp];
  float tC0 = 0.25f * s2[cm] + 0.75f * s2[qx], tC1 = 0.75f * s2[qx] + 0.25f * s2[cp];
  *(float2*)dst = make_float2(0.25f * tA0 + 0.75f * tB0, 0.25f * tA1 + 0.75f * tB1);
  *(float2*)(dst + pitch) = make_float2(0.75f * tB0 + 0.25f * tC0, 0.75f * tB1 + 0.25f * tC1);
}

// ---------------------------------------------------------------------------
// misc: 5 output copies (fp32) + w4 -> bf16 conversion, fused. grid-stride.
// ---------------------------------------------------------------------------
__global__ void misc_kernel(const float* __restrict__ cw4, unsigned short* __restrict__ w4b,
                            const float* __restrict__ xf, const float* __restrict__ w1,
                            const float* __restrict__ w2, const float* __restrict__ w3,
                            const float* __restrict__ w4s, float* __restrict__ out) {
  int idx = blockIdx.x * blockDim.x + threadIdx.x;
  int stride = gridDim.x * blockDim.x;
  for (int i = idx; i < 65536; i += stride) {  // 512*512/4
    float4 v = ld4(cw4 + 4 * i);
    ushort4 u;
    u.x = f2bf(v.x); u.y = f2bf(v.y); u.z = f2bf(v.z); u.w = f2bf(v.w);
    *(ushort4*)(w4b + 4 * i) = u;
  }
  float4* o4 = (float4*)out;
  const size_t W1 = 24117248u / 4;  // o_w1 offset in float4s
  for (int i = idx; i < 8192; i += stride) o4[i] = ((const float4*)xf)[i];
  for (int i = idx; i < 50176; i += stride) o4[W1 + i] = ((const float4*)w1)[i];
  for (int i = idx; i < 25088; i += stride) o4[W1 + 50176 + i] = ((const float4*)w2)[i];
  for (int i = idx; i < 12544; i += stride) o4[W1 + 75264 + i] = ((const float4*)w3)[i];
  for (int i = idx; i < 6272; i += stride) o4[W1 + 87808 + i] = ((const float4*)w4s)[i];
}

// ---------------------------------------------------------------------------
// prep_inT: f4[b][c][p(49)] fp32 -> inT[b][p(64,pad0)][c] bf16 (transposed).
// ---------------------------------------------------------------------------
__global__ void __launch_bounds__(256)
prep_inT(const float* __restrict__ f4, unsigned short* __restrict__ inT) {
  __shared__ unsigned short tile[128][50];
  const int b = blockIdx.x, c0 = blockIdx.y * 128;
  const float* src = f4 + ((size_t)b * 512 + c0) * 49;
  for (int i = threadIdx.x; i < 128 * 49; i += 256) {
    int ci = i / 49, p = i - ci * 49;
    tile[ci][p] = f2bf(src[i]);
  }
  __syncthreads();
  unsigned short* dst = inT + (size_t)b * 64 * 512 + c0;
  for (int i = threadIdx.x; i < 64 * 128; i += 256) {
    int p = i >> 7, ci = i & 127;
    dst[(size_t)p * 512 + ci] = (p < 49) ? tile[ci][p] : (unsigned short)0;
  }
}

// ---------------------------------------------------------------------------
// conv4 as bf16 MFMA GEMM. grid (64, 8): (batch, 64-row m-block).
// 4 waves/block; each wave owns 16 rows x 64 cols. acc layout per m89.
// ---------------------------------------------------------------------------
__global__ void __launch_bounds__(256)
conv4_mfma(const unsigned short* __restrict__ w4b, const unsigned short* __restrict__ inT,
           const float* __restrict__ bias, float* __restrict__ out) {
  const int b = blockIdx.x;
  const int wm = blockIdx.y * 64 + (threadIdx.x >> 6) * 16;
  const int lane = threadIdx.x & 63;
  const int l15 = lane & 15, lg = lane >> 4;

  f32x4 acc[4];
  {
    float bv0 = bias[wm + lg * 4 + 0];
    float bv1 = bias[wm + lg * 4 + 1];
    float bv2 = bias[wm + lg * 4 + 2];
    float bv3 = bias[wm + lg * 4 + 3];
    for (int n = 0; n < 4; ++n) {
      acc[n][0] = bv0; acc[n][1] = bv1; acc[n][2] = bv2; acc[n][3] = bv3;
    }
  }

  const unsigned short* ap = w4b + (size_t)(wm + l15) * 512 + lg * 8;
  const unsigned short* bp = inT + (size_t)b * 64 * 512 + (size_t)l15 * 512 + lg * 8;

#pragma unroll 4
  for (int k0 = 0; k0 < 512; k0 += 32) {
    bf16x8 A  = *(const bf16x8*)(ap + k0);
    bf16x8 B0 = *(const bf16x8*)(bp + k0);
    bf16x8 B1 = *(const bf16x8*)(bp + 16 * 512 + k0);
    bf16x8 B2 = *(const bf16x8*)(bp + 32 * 512 + k0);
    bf16x8 B3 = *(const bf16x8*)(bp + 48 * 512 + k0);
    acc[0] = __builtin_amdgcn_mfma_f32_16x16x32_bf16(A, B0, acc[0], 0, 0, 0);
    acc[1] = __builtin_amdgcn_mfma_f32_16x16x32_bf16(A, B1, acc[1], 0, 0, 0);
    acc[2] = __builtin_amdgcn_mfma_f32_16x16x32_bf16(A, B2, acc[2], 0, 0, 0);
    acc[3] = __builtin_amdgcn_mfma_f32_16x16x32_bf16(A, B3, acc[3], 0, 0, 0);
  }

  float* outb = out + (size_t)b * 512 * 49;
#pragma unroll
  for (int n = 0; n < 4; ++n) {
    int p = n * 16 + l15;
    if (p < 49) {
#pragma unroll
      for (int r = 0; r < 4; ++r) {
        int o = wm + lg * 4 + r;
        outb[(size_t)o * 49 + p] = acc[n][r];
      }
    }
  }
}

// ---------------------------------------------------------------------------
// conv1 (64->64 @28x28) + 2x upsample + per-quadrant perm, fused.
// grid (64, 4, 4): (batch, 16-ch group, 7-row chunk). block 256.
// Tile: 9 src rows (7 + 1 halo each side, edge-clamped at build) x 28 cols.
// ---------------------------------------------------------------------------
__global__ void __launch_bounds__(256)
conv_up_perm1(const float* __restrict__ f, const float* __restrict__ w,
              const float* __restrict__ bias, const int* __restrict__ perms,
              float* __restrict__ out) {
  __shared__ float4 wT[64][4];
  __shared__ float ct[16][9 * 28];
  __shared__ float bs[16];
  __shared__ int inv[4][16];
  const int b = blockIdx.x, o0 = blockIdx.y * 16;
  const int r0 = blockIdx.z * 7;     // first output quad-row of this chunk
  const int base = r0 - 1;           // tile row lr holds global src row clamp(base+lr)
  const int tid = threadIdx.x;

  {
    int og = tid >> 6, c = tid & 63;
    float4 t;
    t.x = w[(o0 + og * 4 + 0) * 64 + c];
    t.y = w[(o0 + og * 4 + 1) * 64 + c];
    t.z = w[(o0 + og * 4 + 2) * 64 + c];
    t.w = w[(o0 + og * 4 + 3) * 64 + c];
    wT[c][og] = t;
  }
  if (tid < 16) bs[tid] = bias[o0 + tid];
  if (tid >= 128 && tid < 192) {
    int t2 = tid - 128;
    int i = t2 >> 4, cl = t2 & 15;
    int c = o0 + cl;
    int r = 0;
    for (int j = 0; j < 64; ++j)
      if (perms[i * 64 + j] == c) r = j;
    inv[i][cl] = r;
  }
  __syncthreads();

  const float* __restrict__ inb = f + (size_t)b * 64 * 784;
  const int og = tid >> 6, pl = tid & 63;

  // conv: 9 rows x 7 float4-groups = 63 units per 4-ch group
  if (pl < 63) {
    int lr = pl / 7, cq = pl % 7;
    int sr = base + lr;
    sr = sr < 0 ? 0 : (sr > 27 ? 27 : sr);
    int p0 = sr * 28 + cq * 4;
    float4 a0 = {0, 0, 0, 0}, a1 = a0, a2 = a0, a3 = a0;
#pragma unroll 4
    for (int c = 0; c < 64; ++c) {
      float4 v = ld4(inb + c * 784 + p0);
      float4 wv = wT[c][og];
      a0.x = fmaf(v.x, wv.x, a0.x); a0.y = fmaf(v.y, wv.x, a0.y);
      a0.z = fmaf(v.z, wv.x, a0.z); a0.w = fmaf(v.w, wv.x, a0.w);
      a1.x = fmaf(v.x, wv.y, a1.x); a1.y = fmaf(v.y, wv.y, a1.y);
      a1.z = fmaf(v.z, wv.y, a1.z); a1.w = fmaf(v.w, wv.y, a1.w);
      a2.x = fmaf(v.x, wv.z, a2.x); a2.y = fmaf(v.y, wv.z, a2.y);
      a2.z = fmaf(v.z, wv.z, a2.z); a2.w = fmaf(v.w, wv.z, a2.w);
      a3.x = fmaf(v.x, wv.w, a3.x); a3.y = fmaf(v.y, wv.w, a3.y);
      a3.z = fmaf(v.z, wv.w, a3.z); a3.w = fmaf(v.w, wv.w, a3.w);
    }
    int lp = lr * 28 + cq * 4;
    float b0 = bs[og * 4 + 0], b1 = bs[og * 4 + 1], b2 = bs[og * 4 + 2], b3 = bs[og * 4 + 3];
    *(float4*)&ct[og * 4 + 0][lp] = make_float4(a0.x + b0, a0.y + b0, a0.z + b0, a0.w + b0);
    *(float4*)&ct[og * 4 + 1][lp] = make_float4(a1.x + b1, a1.y + b1, a1.z + b1, a1.w + b1);
    *(float4*)&ct[og * 4 + 2][lp] = make_float4(a2.x + b2, a2.y + b2, a2.z + b2, a2.w + b2);
    *(float4*)&ct[og * 4 + 3][lp] = make_float4(a3.x + b3, a3.y + b3, a3.z + b3, a3.w + b3);
  }
  __syncthreads();

  // upsample + perm: 16 ch x 7 quad-rows x 28 cols
  const size_t obase = (size_t)b * 64 * 3136;
  for (int i = tid; i < 16 * 196; i += 256) {
    int cl = i / 196;
    int q = i - cl * 196;
    int ly = q / 28, qx = q - ly * 28;
    int qy = r0 + ly;
    int lr = qy - base;  // 1..7; rows lr-1..lr+1 resident
    int qi = ((qy >= 14) ? 2 : 0) + ((qx >= 14) ? 1 : 0);
    int j = inv[qi][cl];
    float* dst = out + obase + (size_t)j * 3136 + (size_t)(2 * qy) * 56 + 2 * qx;
    up_quad_rows(&ct[cl][(lr - 1) * 28], &ct[cl][lr * 28], &ct[cl][(lr + 1) * 28],
                 qx, 28, dst, 56);
  }
}

// ---------------------------------------------------------------------------
// conv2 (128->128 @14x14) + 2x upsample to 28x28.
// grid (64, 4, 2): (batch, 32-ch group, 7-row chunk). block 512.
// ---------------------------------------------------------------------------
__global__ void __launch_bounds__(512)
conv_up2(const float* __restrict__ f, const float* __restrict__ w,
         const float* __restrict__ bias, float* __restrict__ out) {
  __shared__ float4 wT[128][8];
  __shared__ float ct[32][9 * 14];
  __shared__ float bs[32];
  const int b = blockIdx.x, o0 = blockIdx.y * 32;
  const int r0 = blockIdx.z * 7;
  const int base = r0 - 1;
  const int tid = threadIdx.x;

  for (int i = tid; i < 1024; i += 512) {
    int og = i >> 7, c = i & 127;
    float4 t;
    t.x = w[(size_t)(o0 + og * 4 + 0) * 128 + c];
    t.y = w[(size_t)(o0 + og * 4 + 1) * 128 + c];
    t.z = w[(size_t)(o0 + og * 4 + 2) * 128 + c];
    t.w = w[(size_t)(o0 + og * 4 + 3) * 128 + c];
    wT[c][og] = t;
  }
  if (tid < 32) bs[tid] = bias[o0 + tid];
  __syncthreads();

  const float* __restrict__ inb = f + (size_t)b * 128 * 196;
  const int og = tid >> 6, pl = tid & 63;  // og 0..7 -> 4 ch each

  // conv: 9 rows x 7 float2-groups = 63 units per 4-ch group
  if (pl < 63) {
    int lr = pl / 7, cq = pl % 7;
    int sr = base + lr;
    sr = sr < 0 ? 0 : (sr > 13 ? 13 : sr);
    int p0 = sr * 14 + cq * 2;
    float2 a0 = {0, 0}, a1 = a0, a2 = a0, a3 = a0;
#pragma unroll 4
    for (int c = 0; c < 128; ++c) {
      float2 v = ld2(inb + (size_t)c * 196 + p0);
      float4 wv = wT[c][og];
      a0.x = fmaf(v.x, wv.x, a0.x); a0.y = fmaf(v.y, wv.x, a0.y);
      a1.x = fmaf(v.x, wv.y, a1.x); a1.y = fmaf(v.y, wv.y, a1.y);
      a2.x = fmaf(v.x, wv.z, a2.x); a2.y = fmaf(v.y, wv.z, a2.y);
      a3.x = fmaf(v.x, wv.w, a3.x); a3.y = fmaf(v.y, wv.w, a3.y);
    }
    int lp = lr * 14 + cq * 2;
    float b0 = bs[og * 4 + 0], b1 = bs[og * 4 + 1], b2 = bs[og * 4 + 2], b3 = bs[og * 4 + 3];
    *(float2*)&ct[og * 4 + 0][lp] = make_float2(a0.x + b0, a0.y + b0);
    *(float2*)&ct[og * 4 + 1][lp] = make_float2(a1.x + b1, a1.y + b1);
    *(float2*)&ct[og * 4 + 2][lp] = make_float2(a2.x + b2, a2.y + b2);
    *(float2*)&ct[og * 4 + 3][lp] = make_float2(a3.x + b3, a3.y + b3);
  }
  __syncthreads();

  // upsample: 32 ch x 7 quad-rows x 14 cols
  const size_t obase = (size_t)b * 128 * 784;
  for (int i = tid; i < 32 * 98; i += 512) {
    int cl = i / 98;
    int q = i - cl * 98;
    int ly = q / 14, qx = q - ly * 14;
    int qy = r0 + ly;
    int lr = qy - base;
    float* dst = out + obase + (size_t)(o0 + cl) * 784 + (size_t)(2 * qy) * 28 + 2 * qx;
    up_quad_rows(&ct[cl][(lr - 1) * 14], &ct[cl][lr * 14], &ct[cl][(lr + 1) * 14],
                 qx, 14, dst, 28);
  }
}

// ---------------------------------------------------------------------------
// conv3 (128->256 @7x7) + 2x upsample to 14x14. grid (64, 16), block 256.
// 16 out-ch per wg. Full 7x7 tile (no split; tiny).
// ---------------------------------------------------------------------------
__global__ void __launch_bounds__(256)
conv_up3(const float* __restrict__ f, const float* __restrict__ w,
         const float* __restrict__ bias, float* __restrict__ out) {
  __shared__ float wT[128][16];
  __shared__ float ct[16][49];
  __shared__ float bs[16];
  const int b = blockIdx.x, o0 = blockIdx.y * 16;
  const int tid = threadIdx.x;

  for (int i = tid; i < 2048; i += 256) {
    int c = i >> 4, ol = i & 15;
    wT[c][ol] = w[(size_t)(o0 + ol) * 128 + c];
  }
  if (tid < 16) bs[tid] = bias[o0 + tid];
  __syncthreads();

  const float* __restrict__ inb = f + (size_t)b * 128 * 49;
  const int og = tid >> 6, pl = tid & 63;  // og 0..3 -> 4 ch each

  if (pl < 49) {
    float a0 = 0, a1 = 0, a2 = 0, a3 = 0;
#pragma unroll 4
    for (int c = 0; c < 128; ++c) {
      float v = inb[c * 49 + pl];
      float4 wv = *(float4*)&wT[c][og * 4];
      a0 = fmaf(v, wv.x, a0);
      a1 = fmaf(v, wv.y, a1);
      a2 = fmaf(v, wv.z, a2);
      a3 = fmaf(v, wv.w, a3);
    }
    ct[og * 4 + 0][pl] = a0 + bs[og * 4 + 0];
    ct[og * 4 + 1][pl] = a1 + bs[og * 4 + 1];
    ct[og * 4 + 2][pl] = a2 + bs[og * 4 + 2];
    ct[og * 4 + 3][pl] = a3 + bs[og * 4 + 3];
  }
  __syncthreads();

  const size_t obase = (size_t)b * 256 * 196;
  for (int i = tid; i < 16 * 49; i += 256) {
    int cl = i / 49;
    int q = i - cl * 49;
    int qy = q / 7, qx = q - qy * 7;
    int rm = qy > 0 ? qy - 1 : 0, rp = qy < 6 ? qy + 1 : 6;
    float* dst = out + obase + (size_t)(o0 + cl) * 196 + (size_t)(2 * qy) * 14 + 2 * qx;
    up_quad_rows(&ct[cl][rm * 7], &ct[cl][qy * 7], &ct[cl][rp * 7], qx, 7, dst, 14);
  }
}

extern "C" void kernel_launch(void* const* d_in, const int* in_sizes, int n_in,
                              void* d_out, int out_size, void* d_ws, size_t ws_size,
                              hipStream_t stream) {
  const float* f1      = (const float*)d_in[0];
  const float* f2      = (const float*)d_in[1];
  const float* f3      = (const float*)d_in[2];
  const float* f4      = (const float*)d_in[3];
  const float* x_final = (const float*)d_in[4];
  const float* cw1     = (const float*)d_in[5];
  const float* cb1     = (const float*)d_in[6];
  const float* cw2     = (const float*)d_in[7];
  const float* cb2     = (const float*)d_in[8];
  const float* cw3     = (const float*)d_in[9];
  const float* cb3     = (const float*)d_in[10];
  const float* cw4     = (const float*)d_in[11];
  const float* cb4     = (const float*)d_in[12];
  const float* w1      = (const float*)d_in[13];
  const float* w2      = (const float*)d_in[14];
  const float* w3      = (const float*)d_in[15];
  const float* w4      = (const float*)d_in[16];
  const int*   perms   = (const int*)d_in[17];

  float* out = (float*)d_out;
  float* o_aux1 = out + 32768;
  float* o_aux2 = o_aux1 + 12845056;
  float* o_aux3 = o_aux2 + 6422528;
  float* o_aux4 = o_aux3 + 3211264;

  unsigned short* inT = (unsigned short*)d_ws;           // 64*64*512 bf16 = 4 MB
  unsigned short* w4b = inT + (size_t)64 * 64 * 512;     // 512*512 bf16 = 0.5 MB

  misc_kernel<<<512, 256, 0, stream>>>(cw4, w4b, x_final, w1, w2, w3, w4, out);
  prep_inT<<<dim3(BATCH, 4), 256, 0, stream>>>(f4, inT);
  conv_up_perm1<<<dim3(BATCH, 4, 4), 256, 0, stream>>>(f1, cw1, cb1, perms, o_aux1);
  conv4_mfma<<<dim3(BATCH, 8), 256, 0, stream>>>(w4b, inT, cb4, o_aux4);
  conv_up2<<<dim3(BATCH, 4, 2), 512, 0, stream>>>(f2, cw2, cb2, o_aux2);
  conv_up3<<<dim3(BATCH, 16), 256, 0, stream>>>(f3, cw3, cb3, o_aux3);
}

// Round 7
// 76.123 us; speedup vs baseline: 2.4451x; 1.2507x over previous
//
#include <hip/hip_runtime.h>
#include <hip/hip_bf16.h>
#include <cstddef>

typedef __attribute__((ext_vector_type(8))) short bf16x8;
typedef __attribute__((ext_vector_type(4))) float f32x4;

__device__ __forceinline__ float4 ld4(const float* p) { return *(const float4*)p; }
__device__ __forceinline__ float2 ld2(const float* p) { return *(const float2*)p; }
__device__ __forceinline__ unsigned short f2bf(float v) {
  __hip_bfloat16 h = __float2bfloat16(v);
  return *(unsigned short*)&h;
}

// 2x bilinear upsample of one 2x2 quad given three halo-resolved source rows.
__device__ __forceinline__ void up_quad_rows(const float* __restrict__ s0,
                                             const float* __restrict__ s1,
                                             const float* __restrict__ s2,
                                             int qx, int W, float* __restrict__ dst, int pitch) {
  int cm = qx > 0 ? qx - 1 : 0, cp = qx < W - 1 ? qx + 1 : W - 1;
  float tA0 = 0.25f * s0[cm] + 0.75f * s0[qx], tA1 = 0.75f * s0[qx] + 0.25f * s0[cp];
  float tB0 = 0.25f * s1[cm] + 0.75f * s1[qx], tB1 = 0.75f * s1[qx] + 0.25f * s1[cp];
  float tC0 = 0.25f * s2[cm] + 0.75f * s2[qx], tC1 = 0.75f * s2[qx] + 0.25f * s2[cp];
  *(float2*)dst = make_float2(0.25f * tA0 + 0.75f * tB0, 0.25f * tA1 + 0.75f * tB1);
  *(float2*)(dst + pitch) = make_float2(0.75f * tB0 + 0.25f * tC0, 0.75f * tB1 + 0.25f * tC1);
}

// ---------------- LDS unions (typed; no char casts) ----------------
struct PrepS  { unsigned short tile[128][50]; };
struct Conv2S { float4 wT[128][8]; float ct[32][126]; float bs[32]; };
union SmemA   { PrepS prep; Conv2S c2; };

struct Perm1S { float4 wT[64][4]; float ct[16][252]; float bs[16]; int inv[4][16]; };
struct Conv3S { float wT[128][16]; float ct[16][49]; float bs[16]; };
union SmemB   { Perm1S p1; Conv3S c3; };

// ---------------------------------------------------------------------------
// combo512: 512-thread blocks.
//  [0,256)   : prep_inT  (R5 body; b=bid>>2, c0=(bid&3)*128)
//  [256,320) : misc — w4->bf16 + 5 output copies (R5 body, grid-stride)
//  [320,832) : conv2 — R5 conv_up2 VERBATIM (b=t>>3, y=(t>>1)&3, z=t&1)
// ---------------------------------------------------------------------------
__global__ void __launch_bounds__(512)
combo512(const float* __restrict__ f4, unsigned short* __restrict__ inT,
         unsigned short* __restrict__ w4b, const float* __restrict__ cw4,
         const float* __restrict__ xf, const float* __restrict__ w1,
         const float* __restrict__ w2, const float* __restrict__ w3,
         const float* __restrict__ w4s,
         const float* __restrict__ f2, const float* __restrict__ cw2,
         const float* __restrict__ cb2, float* __restrict__ out) {
  __shared__ SmemA sm;
  const int bid = blockIdx.x, tid = threadIdx.x;

  if (bid < 256) {
    // ---- prep_inT: f4[b][c][49] fp32 -> inT[b][p(64,pad0)][c] bf16 ----
    const int b = bid >> 2, c0 = (bid & 3) * 128;
    const float* src = f4 + ((size_t)b * 512 + c0) * 49;
    for (int i = tid; i < 128 * 49; i += 512) {
      int ci = i / 49, p = i - ci * 49;
      sm.prep.tile[ci][p] = f2bf(src[i]);
    }
    __syncthreads();
    unsigned short* dst = inT + (size_t)b * 64 * 512 + c0;
    for (int i = tid; i < 64 * 128; i += 512) {
      int p = i >> 7, ci = i & 127;
      dst[(size_t)p * 512 + ci] = (p < 49) ? sm.prep.tile[ci][p] : (unsigned short)0;
    }
  } else if (bid < 320) {
    // ---- misc: w4 bf16 conversion + output copies ----
    int idx = (bid - 256) * 512 + tid;
    const int stride = 64 * 512;
    for (int i = idx; i < 65536; i += stride) {  // 512*512/4
      float4 v = ld4(cw4 + 4 * i);
      ushort4 u;
      u.x = f2bf(v.x); u.y = f2bf(v.y); u.z = f2bf(v.z); u.w = f2bf(v.w);
      *(ushort4*)(w4b + 4 * i) = u;
    }
    float4* o4 = (float4*)out;
    const size_t W1 = 6029312;  // o_w1 offset in float4s
    for (int i = idx; i < 8192; i += stride) o4[i] = ((const float4*)xf)[i];
    for (int i = idx; i < 50176; i += stride) o4[W1 + i] = ((const float4*)w1)[i];
    for (int i = idx; i < 25088; i += stride) o4[W1 + 50176 + i] = ((const float4*)w2)[i];
    for (int i = idx; i < 12544; i += stride) o4[W1 + 75264 + i] = ((const float4*)w3)[i];
    for (int i = idx; i < 6272; i += stride) o4[W1 + 87808 + i] = ((const float4*)w4s)[i];
  } else {
    // ---- conv2: R5 conv_up2 VERBATIM (32 ch per block, 512 threads) ----
    const int t = bid - 320;
    const int b = t >> 3, o0 = ((t >> 1) & 3) * 32;
    const int r0 = (t & 1) * 7;
    const int base = r0 - 1;
    float* o_aux2 = out + 32768 + 12845056;

    for (int i = tid; i < 1024; i += 512) {
      int og = i >> 7, c = i & 127;
      float4 tt;
      tt.x = cw2[(size_t)(o0 + og * 4 + 0) * 128 + c];
      tt.y = cw2[(size_t)(o0 + og * 4 + 1) * 128 + c];
      tt.z = cw2[(size_t)(o0 + og * 4 + 2) * 128 + c];
      tt.w = cw2[(size_t)(o0 + og * 4 + 3) * 128 + c];
      sm.c2.wT[c][og] = tt;
    }
    if (tid < 32) sm.c2.bs[tid] = cb2[o0 + tid];
    __syncthreads();

    const float* __restrict__ inb = f2 + (size_t)b * 128 * 196;
    const int og = tid >> 6, pl = tid & 63;

    if (pl < 63) {
      int lr = pl / 7, cq = pl % 7;
      int sr = base + lr;
      sr = sr < 0 ? 0 : (sr > 13 ? 13 : sr);
      int p0 = sr * 14 + cq * 2;
      float2 a0 = {0, 0}, a1 = a0, a2 = a0, a3 = a0;
#pragma unroll 4
      for (int c = 0; c < 128; ++c) {
        float2 v = ld2(inb + (size_t)c * 196 + p0);
        float4 wv = sm.c2.wT[c][og];
        a0.x = fmaf(v.x, wv.x, a0.x); a0.y = fmaf(v.y, wv.x, a0.y);
        a1.x = fmaf(v.x, wv.y, a1.x); a1.y = fmaf(v.y, wv.y, a1.y);
        a2.x = fmaf(v.x, wv.z, a2.x); a2.y = fmaf(v.y, wv.z, a2.y);
        a3.x = fmaf(v.x, wv.w, a3.x); a3.y = fmaf(v.y, wv.w, a3.y);
      }
      int lp = lr * 14 + cq * 2;
      float b0 = sm.c2.bs[og * 4 + 0], b1 = sm.c2.bs[og * 4 + 1];
      float b2 = sm.c2.bs[og * 4 + 2], b3 = sm.c2.bs[og * 4 + 3];
      *(float2*)&sm.c2.ct[og * 4 + 0][lp] = make_float2(a0.x + b0, a0.y + b0);
      *(float2*)&sm.c2.ct[og * 4 + 1][lp] = make_float2(a1.x + b1, a1.y + b1);
      *(float2*)&sm.c2.ct[og * 4 + 2][lp] = make_float2(a2.x + b2, a2.y + b2);
      *(float2*)&sm.c2.ct[og * 4 + 3][lp] = make_float2(a3.x + b3, a3.y + b3);
    }
    __syncthreads();

    const size_t obase = (size_t)b * 128 * 784;
    for (int i = tid; i < 32 * 98; i += 512) {
      int cl = i / 98;
      int q = i - cl * 98;
      int ly = q / 14, qx = q - ly * 14;
      int qy = r0 + ly;
      int lr = qy - base;
      float* dst = o_aux2 + obase + (size_t)(o0 + cl) * 784 + (size_t)(2 * qy) * 28 + 2 * qx;
      up_quad_rows(&sm.c2.ct[cl][(lr - 1) * 14], &sm.c2.ct[cl][lr * 14],
                   &sm.c2.ct[cl][(lr + 1) * 14], qx, 14, dst, 28);
    }
  }
}

// ---------------------------------------------------------------------------
// mega256: 256-thread blocks.
//  [0,1024)    perm1 (R6-passed verbatim)
//  [1024,2048) conv3 (R5 verbatim)
//  [2048,2560) conv4 (R5 verbatim; reads w4b/inT from combo512)
// ---------------------------------------------------------------------------
__global__ void __launch_bounds__(256)
mega256(const float* __restrict__ f1, const float* __restrict__ cw1,
        const float* __restrict__ cb1, const int* __restrict__ perms,
        const float* __restrict__ f3, const float* __restrict__ cw3,
        const float* __restrict__ cb3,
        const unsigned short* __restrict__ w4b, const unsigned short* __restrict__ inT,
        const float* __restrict__ cb4, float* __restrict__ out) {
  __shared__ SmemB sm;
  const int bid = blockIdx.x, tid = threadIdx.x;
  float* o_aux1 = out + 32768;
  float* o_aux3 = o_aux1 + 12845056 + 6422528;
  float* o_aux4 = o_aux3 + 3211264;

  if (bid < 1024) {
    // ---- perm1: conv1 + upsample + per-quadrant perm ----
    const int b = bid >> 4, o0 = ((bid >> 2) & 3) * 16;
    const int r0 = (bid & 3) * 7, base = r0 - 1;

    {
      int og = tid >> 6, c = tid & 63;
      float4 t;
      t.x = cw1[(o0 + og * 4 + 0) * 64 + c];
      t.y = cw1[(o0 + og * 4 + 1) * 64 + c];
      t.z = cw1[(o0 + og * 4 + 2) * 64 + c];
      t.w = cw1[(o0 + og * 4 + 3) * 64 + c];
      sm.p1.wT[c][og] = t;
    }
    if (tid < 16) sm.p1.bs[tid] = cb1[o0 + tid];
    if (tid >= 128 && tid < 192) {
      int t2 = tid - 128;
      int i = t2 >> 4, cl = t2 & 15;
      int c = o0 + cl;
      int r = 0;
      for (int j = 0; j < 64; ++j)
        if (perms[i * 64 + j] == c) r = j;
      sm.p1.inv[i][cl] = r;
    }
    __syncthreads();

    const float* __restrict__ inb = f1 + (size_t)b * 64 * 784;
    const int og = tid >> 6, pl = tid & 63;

    if (pl < 63) {
      int lr = pl / 7, cq = pl % 7;
      int sr = base + lr;
      sr = sr < 0 ? 0 : (sr > 27 ? 27 : sr);
      int p0 = sr * 28 + cq * 4;
      float4 a0 = {0, 0, 0, 0}, a1 = a0, a2 = a0, a3 = a0;
#pragma unroll 4
      for (int c = 0; c < 64; ++c) {
        float4 v = ld4(inb + c * 784 + p0);
        float4 wv = sm.p1.wT[c][og];
        a0.x = fmaf(v.x, wv.x, a0.x); a0.y = fmaf(v.y, wv.x, a0.y);
        a0.z = fmaf(v.z, wv.x, a0.z); a0.w = fmaf(v.w, wv.x, a0.w);
        a1.x = fmaf(v.x, wv.y, a1.x); a1.y = fmaf(v.y, wv.y, a1.y);
        a1.z = fmaf(v.z, wv.y, a1.z); a1.w = fmaf(v.w, wv.y, a1.w);
        a2.x = fmaf(v.x, wv.z, a2.x); a2.y = fmaf(v.y, wv.z, a2.y);
        a2.z = fmaf(v.z, wv.z, a2.z); a2.w = fmaf(v.w, wv.z, a2.w);
        a3.x = fmaf(v.x, wv.w, a3.x); a3.y = fmaf(v.y, wv.w, a3.y);
        a3.z = fmaf(v.z, wv.w, a3.z); a3.w = fmaf(v.w, wv.w, a3.w);
      }
      int lp = lr * 28 + cq * 4;
      float b0 = sm.p1.bs[og * 4 + 0], b1 = sm.p1.bs[og * 4 + 1];
      float b2 = sm.p1.bs[og * 4 + 2], b3 = sm.p1.bs[og * 4 + 3];
      *(float4*)&sm.p1.ct[og * 4 + 0][lp] = make_float4(a0.x + b0, a0.y + b0, a0.z + b0, a0.w + b0);
      *(float4*)&sm.p1.ct[og * 4 + 1][lp] = make_float4(a1.x + b1, a1.y + b1, a1.z + b1, a1.w + b1);
      *(float4*)&sm.p1.ct[og * 4 + 2][lp] = make_float4(a2.x + b2, a2.y + b2, a2.z + b2, a2.w + b2);
      *(float4*)&sm.p1.ct[og * 4 + 3][lp] = make_float4(a3.x + b3, a3.y + b3, a3.z + b3, a3.w + b3);
    }
    __syncthreads();

    const size_t obase = (size_t)b * 64 * 3136;
    for (int i = tid; i < 16 * 196; i += 256) {
      int cl = i / 196;
      int q = i - cl * 196;
      int ly = q / 28, qx = q - ly * 28;
      int qy = r0 + ly;
      int lr = ly + 1;
      int qi = ((qy >= 14) ? 2 : 0) + ((qx >= 14) ? 1 : 0);
      int j = sm.p1.inv[qi][cl];
      float* dst = o_aux1 + obase + (size_t)j * 3136 + (size_t)(2 * qy) * 56 + 2 * qx;
      up_quad_rows(&sm.p1.ct[cl][(lr - 1) * 28], &sm.p1.ct[cl][lr * 28],
                   &sm.p1.ct[cl][(lr + 1) * 28], qx, 28, dst, 56);
    }
  } else if (bid < 2048) {
    // ---- conv3: 128->256 @7x7 + upsample ----
    const int t = bid - 1024;
    const int b = t >> 4, o0 = (t & 15) * 16;

    for (int i = tid; i < 2048; i += 256) {
      int c = i >> 4, ol = i & 15;
      sm.c3.wT[c][ol] = cw3[(size_t)(o0 + ol) * 128 + c];
    }
    if (tid < 16) sm.c3.bs[tid] = cb3[o0 + tid];
    __syncthreads();

    const float* __restrict__ inb = f3 + (size_t)b * 128 * 49;
    const int og = tid >> 6, pl = tid & 63;

    if (pl < 49) {
      float a0 = 0, a1 = 0, a2 = 0, a3 = 0;
#pragma unroll 4
      for (int c = 0; c < 128; ++c) {
        float v = inb[c * 49 + pl];
        float4 wv = *(float4*)&sm.c3.wT[c][og * 4];
        a0 = fmaf(v, wv.x, a0);
        a1 = fmaf(v, wv.y, a1);
        a2 = fmaf(v, wv.z, a2);
        a3 = fmaf(v, wv.w, a3);
      }
      sm.c3.ct[og * 4 + 0][pl] = a0 + sm.c3.bs[og * 4 + 0];
      sm.c3.ct[og * 4 + 1][pl] = a1 + sm.c3.bs[og * 4 + 1];
      sm.c3.ct[og * 4 + 2][pl] = a2 + sm.c3.bs[og * 4 + 2];
      sm.c3.ct[og * 4 + 3][pl] = a3 + sm.c3.bs[og * 4 + 3];
    }
    __syncthreads();

    const size_t obase = (size_t)b * 256 * 196;
    for (int i = tid; i < 16 * 49; i += 256) {
      int cl = i / 49;
      int q = i - cl * 49;
      int qy = q / 7, qx = q - qy * 7;
      int rm = qy > 0 ? qy - 1 : 0, rp = qy < 6 ? qy + 1 : 6;
      float* dst = o_aux3 + obase + (size_t)(o0 + cl) * 196 + (size_t)(2 * qy) * 14 + 2 * qx;
      up_quad_rows(&sm.c3.ct[cl][rm * 7], &sm.c3.ct[cl][qy * 7], &sm.c3.ct[cl][rp * 7],
                   qx, 7, dst, 14);
    }
  } else {
    // ---- conv4: bf16 MFMA GEMM (R5 verbatim) ----
    const int t = bid - 2048;
    const int b = t >> 3;
    const int wm = (t & 7) * 64 + (tid >> 6) * 16;
    const int lane = tid & 63;
    const int l15 = lane & 15, lg = lane >> 4;

    f32x4 acc[4];
    {
      float bv0 = cb4[wm + lg * 4 + 0];
      float bv1 = cb4[wm + lg * 4 + 1];
      float bv2 = cb4[wm + lg * 4 + 2];
      float bv3 = cb4[wm + lg * 4 + 3];
      for (int n = 0; n < 4; ++n) {
        acc[n][0] = bv0; acc[n][1] = bv1; acc[n][2] = bv2; acc[n][3] = bv3;
      }
    }

    const unsigned short* ap = w4b + (size_t)(wm + l15) * 512 + lg * 8;
    const unsigned short* bp = inT + (size_t)b * 64 * 512 + (size_t)l15 * 512 + lg * 8;

#pragma unroll 4
    for (int k0 = 0; k0 < 512; k0 += 32) {
      bf16x8 A  = *(const bf16x8*)(ap + k0);
      bf16x8 B0 = *(const bf16x8*)(bp + k0);
      bf16x8 B1 = *(const bf16x8*)(bp + 16 * 512 + k0);
      bf16x8 B2 = *(const bf16x8*)(bp + 32 * 512 + k0);
      bf16x8 B3 = *(const bf16x8*)(bp + 48 * 512 + k0);
      acc[0] = __builtin_amdgcn_mfma_f32_16x16x32_bf16(A, B0, acc[0], 0, 0, 0);
      acc[1] = __builtin_amdgcn_mfma_f32_16x16x32_bf16(A, B1, acc[1], 0, 0, 0);
      acc[2] = __builtin_amdgcn_mfma_f32_16x16x32_bf16(A, B2, acc[2], 0, 0, 0);
      acc[3] = __builtin_amdgcn_mfma_f32_16x16x32_bf16(A, B3, acc[3], 0, 0, 0);
    }

    float* outb = o_aux4 + (size_t)b * 512 * 49;
#pragma unroll
    for (int n = 0; n < 4; ++n) {
      int p = n * 16 + l15;
      if (p < 49) {
#pragma unroll
        for (int r = 0; r < 4; ++r) {
          int o = wm + lg * 4 + r;
          outb[(size_t)o * 49 + p] = acc[n][r];
        }
      }
    }
  }
}

extern "C" void kernel_launch(void* const* d_in, const int* in_sizes, int n_in,
                              void* d_out, int out_size, void* d_ws, size_t ws_size,
                              hipStream_t stream) {
  const float* f1      = (const float*)d_in[0];
  const float* f2      = (const float*)d_in[1];
  const float* f3      = (const float*)d_in[2];
  const float* f4      = (const float*)d_in[3];
  const float* x_final = (const float*)d_in[4];
  const float* cw1     = (const float*)d_in[5];
  const float* cb1     = (const float*)d_in[6];
  const float* cw2     = (const float*)d_in[7];
  const float* cb2     = (const float*)d_in[8];
  const float* cw3     = (const float*)d_in[9];
  const float* cb3     = (const float*)d_in[10];
  const float* cw4     = (const float*)d_in[11];
  const float* cb4     = (const float*)d_in[12];
  const float* w1      = (const float*)d_in[13];
  const float* w2      = (const float*)d_in[14];
  const float* w3      = (const float*)d_in[15];
  const float* w4      = (const float*)d_in[16];
  const int*   perms   = (const int*)d_in[17];

  float* out = (float*)d_out;

  unsigned short* inT = (unsigned short*)d_ws;           // 64*64*512 bf16 = 4 MB
  unsigned short* w4b = inT + (size_t)64 * 64 * 512;     // 512*512 bf16 = 0.5 MB

  combo512<<<832, 512, 0, stream>>>(f4, inT, w4b, cw4, x_final, w1, w2, w3, w4,
                                    f2, cw2, cb2, out);
  mega256<<<2560, 256, 0, stream>>>(f1, cw1, cb1, perms, f3, cw3, cb3,
                                    w4b, inT, cb4, out);
}

// Round 8
// 72.225 us; speedup vs baseline: 2.5770x; 1.0540x over previous
//
#include <hip/hip_runtime.h>
#include <hip/hip_bf16.h>
#include <cstddef>

typedef __attribute__((ext_vector_type(8))) short bf16x8;
typedef __attribute__((ext_vector_type(4))) float f32x4;

__device__ __forceinline__ float4 ld4(const float* p) { return *(const float4*)p; }
__device__ __forceinline__ float2 ld2(const float* p) { return *(const float2*)p; }
__device__ __forceinline__ unsigned short f2bf(float v) {
  __hip_bfloat16 h = __float2bfloat16(v);
  return *(unsigned short*)&h;
}

// 2x bilinear upsample of one 2x2 quad given three halo-resolved source rows.
__device__ __forceinline__ void up_quad_rows(const float* __restrict__ s0,
                                             const float* __restrict__ s1,
                                             const float* __restrict__ s2,
                                             int qx, int W, float* __restrict__ dst, int pitch) {
  int cm = qx > 0 ? qx - 1 : 0, cp = qx < W - 1 ? qx + 1 : W - 1;
  float tA0 = 0.25f * s0[cm] + 0.75f * s0[qx], tA1 = 0.75f * s0[qx] + 0.25f * s0[cp];
  float tB0 = 0.25f * s1[cm] + 0.75f * s1[qx], tB1 = 0.75f * s1[qx] + 0.25f * s1[cp];
  float tC0 = 0.25f * s2[cm] + 0.75f * s2[qx], tC1 = 0.75f * s2[qx] + 0.25f * s2[cp];
  *(float2*)dst = make_float2(0.25f * tA0 + 0.75f * tB0, 0.25f * tA1 + 0.75f * tB1);
  *(float2*)(dst + pitch) = make_float2(0.75f * tB0 + 0.25f * tC0, 0.75f * tB1 + 0.25f * tC1);
}

// ---------------- LDS unions ----------------
struct PrepS  { unsigned short tile[128][50]; };
struct Conv2S { float4 wT[128][8]; float ct[32][126]; float bs[32]; };
union SmemA   { PrepS prep; Conv2S c2; };

struct Perm1S { float4 wT[64][4]; float ct[16][252]; float bs[16]; int inv[4][16]; };
struct Conv3S { float wT[128][16]; float ct[16][49]; float bs[16]; };
union SmemB   { Perm1S p1; Conv3S c3; };

// ---------------------------------------------------------------------------
// combo512: 512-thread blocks.
//  [0,256)   : prep_inT
//  [256,320) : misc — w4->bf16 + 5 output copies
//  [320,832) : conv2 (R5/R7 geometry; ping-pong prefetched loads)
// ---------------------------------------------------------------------------
__global__ void __launch_bounds__(512)
combo512(const float* __restrict__ f4, unsigned short* __restrict__ inT,
         unsigned short* __restrict__ w4b, const float* __restrict__ cw4,
         const float* __restrict__ xf, const float* __restrict__ w1,
         const float* __restrict__ w2, const float* __restrict__ w3,
         const float* __restrict__ w4s,
         const float* __restrict__ f2, const float* __restrict__ cw2,
         const float* __restrict__ cb2, float* __restrict__ out) {
  __shared__ SmemA sm;
  const int bid = blockIdx.x, tid = threadIdx.x;

  if (bid < 256) {
    // ---- prep_inT: f4[b][c][49] fp32 -> inT[b][p(64,pad0)][c] bf16 ----
    const int b = bid >> 2, c0 = (bid & 3) * 128;
    const float* src = f4 + ((size_t)b * 512 + c0) * 49;
    for (int i = tid; i < 128 * 49; i += 512) {
      int ci = i / 49, p = i - ci * 49;
      sm.prep.tile[ci][p] = f2bf(src[i]);
    }
    __syncthreads();
    unsigned short* dst = inT + (size_t)b * 64 * 512 + c0;
    for (int i = tid; i < 64 * 128; i += 512) {
      int p = i >> 7, ci = i & 127;
      dst[(size_t)p * 512 + ci] = (p < 49) ? sm.prep.tile[ci][p] : (unsigned short)0;
    }
  } else if (bid < 320) {
    // ---- misc ----
    int idx = (bid - 256) * 512 + tid;
    const int stride = 64 * 512;
    for (int i = idx; i < 65536; i += stride) {
      float4 v = ld4(cw4 + 4 * i);
      ushort4 u;
      u.x = f2bf(v.x); u.y = f2bf(v.y); u.z = f2bf(v.z); u.w = f2bf(v.w);
      *(ushort4*)(w4b + 4 * i) = u;
    }
    float4* o4 = (float4*)out;
    const size_t W1 = 6029312;  // o_w1 offset in float4s
    for (int i = idx; i < 8192; i += stride) o4[i] = ((const float4*)xf)[i];
    for (int i = idx; i < 50176; i += stride) o4[W1 + i] = ((const float4*)w1)[i];
    for (int i = idx; i < 25088; i += stride) o4[W1 + 50176 + i] = ((const float4*)w2)[i];
    for (int i = idx; i < 12544; i += stride) o4[W1 + 75264 + i] = ((const float4*)w3)[i];
    for (int i = idx; i < 6272; i += stride) o4[W1 + 87808 + i] = ((const float4*)w4s)[i];
  } else {
    // ---- conv2: 128->128 @14x14, 32 och, 7-row chunk ----
    const int t = bid - 320;
    const int b = t >> 3, o0 = ((t >> 1) & 3) * 32;
    const int r0 = (t & 1) * 7;
    const int base = r0 - 1;
    float* o_aux2 = out + 32768 + 12845056;

    for (int i = tid; i < 1024; i += 512) {
      int og = i >> 7, c = i & 127;
      float4 tt;
      tt.x = cw2[(size_t)(o0 + og * 4 + 0) * 128 + c];
      tt.y = cw2[(size_t)(o0 + og * 4 + 1) * 128 + c];
      tt.z = cw2[(size_t)(o0 + og * 4 + 2) * 128 + c];
      tt.w = cw2[(size_t)(o0 + og * 4 + 3) * 128 + c];
      sm.c2.wT[c][og] = tt;
    }
    if (tid < 32) sm.c2.bs[tid] = cb2[o0 + tid];
    __syncthreads();

    const float* __restrict__ inb = f2 + (size_t)b * 128 * 196;
    const int og = tid >> 6, pl = tid & 63;

    if (pl < 63) {
      int lr = pl / 7, cq = pl % 7;
      int sr = base + lr;
      sr = sr < 0 ? 0 : (sr > 13 ? 13 : sr);
      const float* g = inb + sr * 14 + cq * 2;  // c-stride 196
      float2 a0 = {0, 0}, a1 = a0, a2 = a0, a3 = a0;
      float2 p0, p1, p2, p3, p4, p5, p6, p7, q0, q1, q2, q3, q4, q5, q6, q7;

#define C2_FMA(V, CC) { float4 wv = sm.c2.wT[(CC)][og];            \
      a0.x = fmaf(V.x, wv.x, a0.x); a0.y = fmaf(V.y, wv.x, a0.y);  \
      a1.x = fmaf(V.x, wv.y, a1.x); a1.y = fmaf(V.y, wv.y, a1.y);  \
      a2.x = fmaf(V.x, wv.z, a2.x); a2.y = fmaf(V.y, wv.z, a2.y);  \
      a3.x = fmaf(V.x, wv.w, a3.x); a3.y = fmaf(V.y, wv.w, a3.y); }
#define C2_LD8(P, CB)                                                  \
      P##0 = ld2(g + ((CB) + 0) * 196); P##1 = ld2(g + ((CB) + 1) * 196); \
      P##2 = ld2(g + ((CB) + 2) * 196); P##3 = ld2(g + ((CB) + 3) * 196); \
      P##4 = ld2(g + ((CB) + 4) * 196); P##5 = ld2(g + ((CB) + 5) * 196); \
      P##6 = ld2(g + ((CB) + 6) * 196); P##7 = ld2(g + ((CB) + 7) * 196);
#define C2_FM8(P, CB)                                            \
      C2_FMA(P##0, (CB) + 0) C2_FMA(P##1, (CB) + 1)              \
      C2_FMA(P##2, (CB) + 2) C2_FMA(P##3, (CB) + 3)              \
      C2_FMA(P##4, (CB) + 4) C2_FMA(P##5, (CB) + 5)              \
      C2_FMA(P##6, (CB) + 6) C2_FMA(P##7, (CB) + 7)

      C2_LD8(p, 0)  C2_LD8(q, 8)
      C2_FM8(p, 0)   C2_LD8(p, 16)
      C2_FM8(q, 8)   C2_LD8(q, 24)
      C2_FM8(p, 16)  C2_LD8(p, 32)
      C2_FM8(q, 24)  C2_LD8(q, 40)
      C2_FM8(p, 32)  C2_LD8(p, 48)
      C2_FM8(q, 40)  C2_LD8(q, 56)
      C2_FM8(p, 48)  C2_LD8(p, 64)
      C2_FM8(q, 56)  C2_LD8(q, 72)
      C2_FM8(p, 64)  C2_LD8(p, 80)
      C2_FM8(q, 72)  C2_LD8(q, 88)
      C2_FM8(p, 80)  C2_LD8(p, 96)
      C2_FM8(q, 88)  C2_LD8(q, 104)
      C2_FM8(p, 96)  C2_LD8(p, 112)
      C2_FM8(q, 104) C2_LD8(q, 120)
      C2_FM8(p, 112)
      C2_FM8(q, 120)

      int lp = lr * 14 + cq * 2;
      float b0 = sm.c2.bs[og * 4 + 0], b1 = sm.c2.bs[og * 4 + 1];
      float b2 = sm.c2.bs[og * 4 + 2], b3 = sm.c2.bs[og * 4 + 3];
      *(float2*)&sm.c2.ct[og * 4 + 0][lp] = make_float2(a0.x + b0, a0.y + b0);
      *(float2*)&sm.c2.ct[og * 4 + 1][lp] = make_float2(a1.x + b1, a1.y + b1);
      *(float2*)&sm.c2.ct[og * 4 + 2][lp] = make_float2(a2.x + b2, a2.y + b2);
      *(float2*)&sm.c2.ct[og * 4 + 3][lp] = make_float2(a3.x + b3, a3.y + b3);
    }
    __syncthreads();

    const size_t obase = (size_t)b * 128 * 784;
    for (int i = tid; i < 32 * 98; i += 512) {
      int cl = i / 98;
      int q = i - cl * 98;
      int ly = q / 14, qx = q - ly * 14;
      int qy = r0 + ly;
      int lr = qy - base;
      float* dst = o_aux2 + obase + (size_t)(o0 + cl) * 784 + (size_t)(2 * qy) * 28 + 2 * qx;
      up_quad_rows(&sm.c2.ct[cl][(lr - 1) * 14], &sm.c2.ct[cl][lr * 14],
                   &sm.c2.ct[cl][(lr + 1) * 14], qx, 14, dst, 28);
    }
  }
}

// ---------------------------------------------------------------------------
// mega256: 256-thread blocks.
//  [0,1024)    perm1 (ping-pong prefetched conv loads)
//  [1024,2048) conv3 (ping-pong prefetched conv loads)
//  [2048,2560) conv4 (R7 verbatim)
// ---------------------------------------------------------------------------
__global__ void __launch_bounds__(256)
mega256(const float* __restrict__ f1, const float* __restrict__ cw1,
        const float* __restrict__ cb1, const int* __restrict__ perms,
        const float* __restrict__ f3, const float* __restrict__ cw3,
        const float* __restrict__ cb3,
        const unsigned short* __restrict__ w4b, const unsigned short* __restrict__ inT,
        const float* __restrict__ cb4, float* __restrict__ out) {
  __shared__ SmemB sm;
  const int bid = blockIdx.x, tid = threadIdx.x;
  float* o_aux1 = out + 32768;
  float* o_aux3 = o_aux1 + 12845056 + 6422528;
  float* o_aux4 = o_aux3 + 3211264;

  if (bid < 1024) {
    // ---- perm1: conv1 + upsample + per-quadrant perm ----
    const int b = bid >> 4, o0 = ((bid >> 2) & 3) * 16;
    const int r0 = (bid & 3) * 7, base = r0 - 1;

    {
      int og = tid >> 6, c = tid & 63;
      float4 t;
      t.x = cw1[(o0 + og * 4 + 0) * 64 + c];
      t.y = cw1[(o0 + og * 4 + 1) * 64 + c];
      t.z = cw1[(o0 + og * 4 + 2) * 64 + c];
      t.w = cw1[(o0 + og * 4 + 3) * 64 + c];
      sm.p1.wT[c][og] = t;
    }
    if (tid < 16) sm.p1.bs[tid] = cb1[o0 + tid];
    if (tid >= 128 && tid < 192) {
      int t2 = tid - 128;
      int i = t2 >> 4, cl = t2 & 15;
      int c = o0 + cl;
      int r = 0;
      for (int j = 0; j < 64; ++j)
        if (perms[i * 64 + j] == c) r = j;
      sm.p1.inv[i][cl] = r;
    }
    __syncthreads();

    const float* __restrict__ inb = f1 + (size_t)b * 64 * 784;
    const int og = tid >> 6, pl = tid & 63;

    if (pl < 63) {
      int lr = pl / 7, cq = pl % 7;
      int sr = base + lr;
      sr = sr < 0 ? 0 : (sr > 27 ? 27 : sr);
      const float* g = inb + sr * 28 + cq * 4;  // c-stride 784
      float4 a0 = {0, 0, 0, 0}, a1 = a0, a2 = a0, a3 = a0;
      float4 p0, p1, p2, p3, p4, p5, p6, p7, q0, q1, q2, q3, q4, q5, q6, q7;

#define C1_FMA(V, CC) { float4 wv = sm.p1.wT[(CC)][og];            \
      a0.x = fmaf(V.x, wv.x, a0.x); a0.y = fmaf(V.y, wv.x, a0.y);  \
      a0.z = fmaf(V.z, wv.x, a0.z); a0.w = fmaf(V.w, wv.x, a0.w);  \
      a1.x = fmaf(V.x, wv.y, a1.x); a1.y = fmaf(V.y, wv.y, a1.y);  \
      a1.z = fmaf(V.z, wv.y, a1.z); a1.w = fmaf(V.w, wv.y, a1.w);  \
      a2.x = fmaf(V.x, wv.z, a2.x); a2.y = fmaf(V.y, wv.z, a2.y);  \
      a2.z = fmaf(V.z, wv.z, a2.z); a2.w = fmaf(V.w, wv.z, a2.w);  \
      a3.x = fmaf(V.x, wv.w, a3.x); a3.y = fmaf(V.y, wv.w, a3.y);  \
      a3.z = fmaf(V.z, wv.w, a3.z); a3.w = fmaf(V.w, wv.w, a3.w); }
#define C1_LD8(P, CB)                                                  \
      P##0 = ld4(g + ((CB) + 0) * 784); P##1 = ld4(g + ((CB) + 1) * 784); \
      P##2 = ld4(g + ((CB) + 2) * 784); P##3 = ld4(g + ((CB) + 3) * 784); \
      P##4 = ld4(g + ((CB) + 4) * 784); P##5 = ld4(g + ((CB) + 5) * 784); \
      P##6 = ld4(g + ((CB) + 6) * 784); P##7 = ld4(g + ((CB) + 7) * 784);
#define C1_FM8(P, CB)                                            \
      C1_FMA(P##0, (CB) + 0) C1_FMA(P##1, (CB) + 1)              \
      C1_FMA(P##2, (CB) + 2) C1_FMA(P##3, (CB) + 3)              \
      C1_FMA(P##4, (CB) + 4) C1_FMA(P##5, (CB) + 5)              \
      C1_FMA(P##6, (CB) + 6) C1_FMA(P##7, (CB) + 7)

      C1_LD8(p, 0)  C1_LD8(q, 8)
      C1_FM8(p, 0)  C1_LD8(p, 16)
      C1_FM8(q, 8)  C1_LD8(q, 24)
      C1_FM8(p, 16) C1_LD8(p, 32)
      C1_FM8(q, 24) C1_LD8(q, 40)
      C1_FM8(p, 32) C1_LD8(p, 48)
      C1_FM8(q, 40) C1_LD8(q, 56)
      C1_FM8(p, 48)
      C1_FM8(q, 56)

      int lp = lr * 28 + cq * 4;
      float b0 = sm.p1.bs[og * 4 + 0], b1 = sm.p1.bs[og * 4 + 1];
      float b2 = sm.p1.bs[og * 4 + 2], b3 = sm.p1.bs[og * 4 + 3];
      *(float4*)&sm.p1.ct[og * 4 + 0][lp] = make_float4(a0.x + b0, a0.y + b0, a0.z + b0, a0.w + b0);
      *(float4*)&sm.p1.ct[og * 4 + 1][lp] = make_float4(a1.x + b1, a1.y + b1, a1.z + b1, a1.w + b1);
      *(float4*)&sm.p1.ct[og * 4 + 2][lp] = make_float4(a2.x + b2, a2.y + b2, a2.z + b2, a2.w + b2);
      *(float4*)&sm.p1.ct[og * 4 + 3][lp] = make_float4(a3.x + b3, a3.y + b3, a3.z + b3, a3.w + b3);
    }
    __syncthreads();

    const size_t obase = (size_t)b * 64 * 3136;
    for (int i = tid; i < 16 * 196; i += 256) {
      int cl = i / 196;
      int q = i - cl * 196;
      int ly = q / 28, qx = q - ly * 28;
      int qy = r0 + ly;
      int lr = ly + 1;
      int qi = ((qy >= 14) ? 2 : 0) + ((qx >= 14) ? 1 : 0);
      int j = sm.p1.inv[qi][cl];
      float* dst = o_aux1 + obase + (size_t)j * 3136 + (size_t)(2 * qy) * 56 + 2 * qx;
      up_quad_rows(&sm.p1.ct[cl][(lr - 1) * 28], &sm.p1.ct[cl][lr * 28],
                   &sm.p1.ct[cl][(lr + 1) * 28], qx, 28, dst, 56);
    }
  } else if (bid < 2048) {
    // ---- conv3: 128->256 @7x7 + upsample ----
    const int t = bid - 1024;
    const int b = t >> 4, o0 = (t & 15) * 16;

    for (int i = tid; i < 2048; i += 256) {
      int c = i >> 4, ol = i & 15;
      sm.c3.wT[c][ol] = cw3[(size_t)(o0 + ol) * 128 + c];
    }
    if (tid < 16) sm.c3.bs[tid] = cb3[o0 + tid];
    __syncthreads();

    const float* __restrict__ inb = f3 + (size_t)b * 128 * 49;
    const int og = tid >> 6, pl = tid & 63;

    if (pl < 49) {
      const float* g = inb + pl;  // c-stride 49
      float a0 = 0, a1 = 0, a2 = 0, a3 = 0;
      float p0, p1, p2, p3, p4, p5, p6, p7, q0, q1, q2, q3, q4, q5, q6, q7;

#define C3_FMA(V, CC) { float4 wv = *(float4*)&sm.c3.wT[(CC)][og * 4]; \
      a0 = fmaf(V, wv.x, a0); a1 = fmaf(V, wv.y, a1);                  \
      a2 = fmaf(V, wv.z, a2); a3 = fmaf(V, wv.w, a3); }
#define C3_LD8(P, CB)                                              \
      P##0 = g[((CB) + 0) * 49]; P##1 = g[((CB) + 1) * 49];        \
      P##2 = g[((CB) + 2) * 49]; P##3 = g[((CB) + 3) * 49];        \
      P##4 = g[((CB) + 4) * 49]; P##5 = g[((CB) + 5) * 49];        \
      P##6 = g[((CB) + 6) * 49]; P##7 = g[((CB) + 7) * 49];
#define C3_FM8(P, CB)                                            \
      C3_FMA(P##0, (CB) + 0) C3_FMA(P##1, (CB) + 1)              \
      C3_FMA(P##2, (CB) + 2) C3_FMA(P##3, (CB) + 3)              \
      C3_FMA(P##4, (CB) + 4) C3_FMA(P##5, (CB) + 5)              \
      C3_FMA(P##6, (CB) + 6) C3_FMA(P##7, (CB) + 7)

      C3_LD8(p, 0)  C3_LD8(q, 8)
      C3_FM8(p, 0)   C3_LD8(p, 16)
      C3_FM8(q, 8)   C3_LD8(q, 24)
      C3_FM8(p, 16)  C3_LD8(p, 32)
      C3_FM8(q, 24)  C3_LD8(q, 40)
      C3_FM8(p, 32)  C3_LD8(p, 48)
      C3_FM8(q, 40)  C3_LD8(q, 56)
      C3_FM8(p, 48)  C3_LD8(p, 64)
      C3_FM8(q, 56)  C3_LD8(q, 72)
      C3_FM8(p, 64)  C3_LD8(p, 80)
      C3_FM8(q, 72)  C3_LD8(q, 88)
      C3_FM8(p, 80)  C3_LD8(p, 96)
      C3_FM8(q, 88)  C3_LD8(q, 104)
      C3_FM8(p, 96)  C3_LD8(p, 112)
      C3_FM8(q, 104) C3_LD8(q, 120)
      C3_FM8(p, 112)
      C3_FM8(q, 120)

      sm.c3.ct[og * 4 + 0][pl] = a0 + sm.c3.bs[og * 4 + 0];
      sm.c3.ct[og * 4 + 1][pl] = a1 + sm.c3.bs[og * 4 + 1];
      sm.c3.ct[og * 4 + 2][pl] = a2 + sm.c3.bs[og * 4 + 2];
      sm.c3.ct[og * 4 + 3][pl] = a3 + sm.c3.bs[og * 4 + 3];
    }
    __syncthreads();

    const size_t obase = (size_t)b * 256 * 196;
    for (int i = tid; i < 16 * 49; i += 256) {
      int cl = i / 49;
      int q = i - cl * 49;
      int qy = q / 7, qx = q - qy * 7;
      int rm = qy > 0 ? qy - 1 : 0, rp = qy < 6 ? qy + 1 : 6;
      float* dst = o_aux3 + obase + (size_t)(o0 + cl) * 196 + (size_t)(2 * qy) * 14 + 2 * qx;
      up_quad_rows(&sm.c3.ct[cl][rm * 7], &sm.c3.ct[cl][qy * 7], &sm.c3.ct[cl][rp * 7],
                   qx, 7, dst, 14);
    }
  } else {
    // ---- conv4: bf16 MFMA GEMM (verbatim) ----
    const int t = bid - 2048;
    const int b = t >> 3;
    const int wm = (t & 7) * 64 + (tid >> 6) * 16;
    const int lane = tid & 63;
    const int l15 = lane & 15, lg = lane >> 4;

    f32x4 acc[4];
    {
      float bv0 = cb4[wm + lg * 4 + 0];
      float bv1 = cb4[wm + lg * 4 + 1];
      float bv2 = cb4[wm + lg * 4 + 2];
      float bv3 = cb4[wm + lg * 4 + 3];
      for (int n = 0; n < 4; ++n) {
        acc[n][0] = bv0; acc[n][1] = bv1; acc[n][2] = bv2; acc[n][3] = bv3;
      }
    }

    const unsigned short* ap = w4b + (size_t)(wm + l15) * 512 + lg * 8;
    const unsigned short* bp = inT + (size_t)b * 64 * 512 + (size_t)l15 * 512 + lg * 8;

#pragma unroll 4
    for (int k0 = 0; k0 < 512; k0 += 32) {
      bf16x8 A  = *(const bf16x8*)(ap + k0);
      bf16x8 B0 = *(const bf16x8*)(bp + k0);
      bf16x8 B1 = *(const bf16x8*)(bp + 16 * 512 + k0);
      bf16x8 B2 = *(const bf16x8*)(bp + 32 * 512 + k0);
      bf16x8 B3 = *(const bf16x8*)(bp + 48 * 512 + k0);
      acc[0] = __builtin_amdgcn_mfma_f32_16x16x32_bf16(A, B0, acc[0], 0, 0, 0);
      acc[1] = __builtin_amdgcn_mfma_f32_16x16x32_bf16(A, B1, acc[1], 0, 0, 0);
      acc[2] = __builtin_amdgcn_mfma_f32_16x16x32_bf16(A, B2, acc[2], 0, 0, 0);
      acc[3] = __builtin_amdgcn_mfma_f32_16x16x32_bf16(A, B3, acc[3], 0, 0, 0);
    }

    float* outb = o_aux4 + (size_t)b * 512 * 49;
#pragma unroll
    for (int n = 0; n < 4; ++n) {
      int p = n * 16 + l15;
      if (p < 49) {
#pragma unroll
        for (int r = 0; r < 4; ++r) {
          int o = wm + lg * 4 + r;
          outb[(size_t)o * 49 + p] = acc[n][r];
        }
      }
    }
  }
}

extern "C" void kernel_launch(void* const* d_in, const int* in_sizes, int n_in,
                              void* d_out, int out_size, void* d_ws, size_t ws_size,
                              hipStream_t stream) {
  const float* f1      = (const float*)d_in[0];
  const float* f2      = (const float*)d_in[1];
  const float* f3      = (const float*)d_in[2];
  const float* f4      = (const float*)d_in[3];
  const float* x_final = (const float*)d_in[4];
  const float* cw1     = (const float*)d_in[5];
  const float* cb1     = (const float*)d_in[6];
  const float* cw2     = (const float*)d_in[7];
  const float* cb2     = (const float*)d_in[8];
  const float* cw3     = (const float*)d_in[9];
  const float* cb3     = (const float*)d_in[10];
  const float* cw4     = (const float*)d_in[11];
  const float* cb4     = (const float*)d_in[12];
  const float* w1      = (const float*)d_in[13];
  const float* w2      = (const float*)d_in[14];
  const float* w3      = (const float*)d_in[15];
  const float* w4      = (const float*)d_in[16];
  const int*   perms   = (const int*)d_in[17];

  float* out = (float*)d_out;

  unsigned short* inT = (unsigned short*)d_ws;           // 64*64*512 bf16 = 4 MB
  unsigned short* w4b = inT + (size_t)64 * 64 * 512;     // 512*512 bf16 = 0.5 MB

  combo512<<<832, 512, 0, stream>>>(f4, inT, w4b, cw4, x_final, w1, w2, w3, w4,
                                    f2, cw2, cb2, out);
  mega256<<<2560, 256, 0, stream>>>(f1, cw1, cb1, perms, f3, cw3, cb3,
                                    w4b, inT, cb4, out);
}

// Round 9
// 59.281 us; speedup vs baseline: 3.1397x; 1.2183x over previous
//
#include <hip/hip_runtime.h>
#include <hip/hip_bf16.h>
#include <cstddef>

typedef __attribute__((ext_vector_type(8))) short bf16x8;
typedef __attribute__((ext_vector_type(4))) float f32x4;

__device__ __forceinline__ float4 ld4(const float* p) { return *(const float4*)p; }
__device__ __forceinline__ unsigned short f2bf(float v) {
  __hip_bfloat16 h = __float2bfloat16(v);
  return *(unsigned short*)&h;
}

// 2x bilinear upsample of one 2x2 quad given three halo-resolved source rows.
__device__ __forceinline__ void up_quad_rows(const float* __restrict__ s0,
                                             const float* __restrict__ s1,
                                             const float* __restrict__ s2,
                                             int qx, int W, float* __restrict__ dst, int pitch) {
  int cm = qx > 0 ? qx - 1 : 0, cp = qx < W - 1 ? qx + 1 : W - 1;
  float tA0 = 0.25f * s0[cm] + 0.75f * s0[qx], tA1 = 0.75f * s0[qx] + 0.25f * s0[cp];
  float tB0 = 0.25f * s1[cm] + 0.75f * s1[qx], tB1 = 0.75f * s1[qx] + 0.25f * s1[cp];
  float tC0 = 0.25f * s2[cm] + 0.75f * s2[qx], tC1 = 0.75f * s2[qx] + 0.25f * s2[cp];
  *(float2*)dst = make_float2(0.25f * tA0 + 0.75f * tB0, 0.25f * tA1 + 0.75f * tB1);
  *(float2*)(dst + pitch) = make_float2(0.75f * tB0 + 0.25f * tC0, 0.75f * tB1 + 0.25f * tC1);
}

// ---------------------------------------------------------------------------
// setup256: one launch, 768 blocks x 256 thr.
//  [0,256)   inT : f4 -> [b][p(64,pad0)][c512] bf16   (R5 prep_inT, proven)
//  [256,512) f1T : f1 -> [b][p784][c64]  bf16
//  [512,640) f2T : f2 -> [b][p196][c128] bf16
//  [640,704) f3T : f3 -> [b][p(64,pad0)][c128] bf16
//  [704,768) misc: w1..w4 -> bf16 + 5 fp32 output copies
// ---------------------------------------------------------------------------
__global__ void __launch_bounds__(256)
setup256(const float* __restrict__ f1, const float* __restrict__ f2,
         const float* __restrict__ f3, const float* __restrict__ f4,
         const float* __restrict__ cw1, const float* __restrict__ cw2,
         const float* __restrict__ cw3, const float* __restrict__ cw4,
         const float* __restrict__ xf, const float* __restrict__ w1,
         const float* __restrict__ w2, const float* __restrict__ w3,
         const float* __restrict__ w4s,
         unsigned short* __restrict__ f1T, unsigned short* __restrict__ f2T,
         unsigned short* __restrict__ f3T, unsigned short* __restrict__ inT,
         unsigned short* __restrict__ w1b, unsigned short* __restrict__ w2b,
         unsigned short* __restrict__ w3b, unsigned short* __restrict__ w4b,
         float* __restrict__ out) {
  __shared__ unsigned short stile[12800];
  const int bid = blockIdx.x, tid = threadIdx.x;

  if (bid < 256) {
    // ---- inT (f4 transpose), R5-proven body ----
    const int b = bid >> 2, c0 = (bid & 3) * 128;
    const float* src = f4 + ((size_t)b * 512 + c0) * 49;
    for (int i = tid; i < 128 * 49; i += 256) {
      int ci = i / 49, p = i - ci * 49;
      stile[ci * 50 + p] = f2bf(src[i]);
    }
    __syncthreads();
    unsigned short* dst = inT + (size_t)b * 64 * 512 + c0;
    for (int i = tid; i < 64 * 128; i += 256) {
      int p = i >> 7, ci = i & 127;
      dst[(size_t)p * 512 + ci] = (p < 49) ? stile[ci * 50 + p] : (unsigned short)0;
    }
  } else if (bid < 512) {
    // ---- f1T: per (b, quarter q) 196-px chunk ----
    const int t = bid - 256, b = t >> 2, q = t & 3;
    const float* src = f1 + (size_t)b * 64 * 784 + q * 196;
    for (int i = tid; i < 64 * 196; i += 256) {
      int ci = i / 196, px = i - ci * 196;
      stile[ci * 196 + px] = f2bf(src[(size_t)ci * 784 + px]);
    }
    __syncthreads();
    unsigned short* dst = f1T + ((size_t)b * 784 + q * 196) * 64;
    for (int i = tid; i < 196 * 8; i += 256) {
      int p = i >> 3, cg = (i & 7) * 8;
      unsigned short tmp[8];
#pragma unroll
      for (int k = 0; k < 8; ++k) tmp[k] = stile[(cg + k) * 196 + p];
      *(ushort4*)(dst + (size_t)p * 64 + cg) = *(ushort4*)tmp;
      *(ushort4*)(dst + (size_t)p * 64 + cg + 4) = *(ushort4*)(tmp + 4);
    }
  } else if (bid < 640) {
    // ---- f2T: per (b, half h) 98-px chunk ----
    const int t = bid - 512, b = t >> 1, h = t & 1;
    const float* src = f2 + (size_t)b * 128 * 196 + h * 98;
    for (int i = tid; i < 128 * 98; i += 256) {
      int ci = i / 98, px = i - ci * 98;
      stile[ci * 98 + px] = f2bf(src[(size_t)ci * 196 + px]);
    }
    __syncthreads();
    unsigned short* dst = f2T + ((size_t)b * 196 + h * 98) * 128;
    for (int i = tid; i < 98 * 16; i += 256) {
      int p = i >> 4, cg = (i & 15) * 8;
      unsigned short tmp[8];
#pragma unroll
      for (int k = 0; k < 8; ++k) tmp[k] = stile[(cg + k) * 98 + p];
      *(ushort4*)(dst + (size_t)p * 128 + cg) = *(ushort4*)tmp;
      *(ushort4*)(dst + (size_t)p * 128 + cg + 4) = *(ushort4*)(tmp + 4);
    }
  } else if (bid < 704) {
    // ---- f3T: per b, pad p to 64 rows with zeros ----
    const int b = bid - 640;
    const float* src = f3 + (size_t)b * 128 * 49;
    for (int i = tid; i < 128 * 49; i += 256) {
      int ci = i / 49, px = i - ci * 49;
      stile[ci * 49 + px] = f2bf(src[i]);
    }
    __syncthreads();
    unsigned short* dst = f3T + (size_t)b * 64 * 128;
    for (int i = tid; i < 64 * 16; i += 256) {
      int p = i >> 4, cg = (i & 15) * 8;
      unsigned short tmp[8];
#pragma unroll
      for (int k = 0; k < 8; ++k) tmp[k] = (p < 49) ? stile[(cg + k) * 49 + p] : (unsigned short)0;
      *(ushort4*)(dst + (size_t)p * 128 + cg) = *(ushort4*)tmp;
      *(ushort4*)(dst + (size_t)p * 128 + cg + 4) = *(ushort4*)(tmp + 4);
    }
  } else {
    // ---- misc: weight bf16 conversions + output copies ----
    int idx = (bid - 704) * 256 + tid;
    const int stride = 64 * 256;
#define CVT(DST, SRC, N)                                          \
    for (int i = idx; i < (N); i += stride) {                     \
      float4 v = ld4((SRC) + 4 * i);                              \
      ushort4 u;                                                  \
      u.x = f2bf(v.x); u.y = f2bf(v.y); u.z = f2bf(v.z); u.w = f2bf(v.w); \
      *(ushort4*)((DST) + 4 * i) = u;                             \
    }
    CVT(w4b, cw4, 65536)
    CVT(w1b, cw1, 1024)
    CVT(w2b, cw2, 4096)
    CVT(w3b, cw3, 8192)
#undef CVT
    float4* o4 = (float4*)out;
    const size_t W1 = 6029312;  // o_w1 offset in float4s
    for (int i = idx; i < 8192; i += stride) o4[i] = ((const float4*)xf)[i];
    for (int i = idx; i < 50176; i += stride) o4[W1 + i] = ((const float4*)w1)[i];
    for (int i = idx; i < 25088; i += stride) o4[W1 + 50176 + i] = ((const float4*)w2)[i];
    for (int i = idx; i < 12544; i += stride) o4[W1 + 75264 + i] = ((const float4*)w3)[i];
    for (int i = idx; i < 6272; i += stride) o4[W1 + 87808 + i] = ((const float4*)w4s)[i];
  }
}

// ---------------- mega LDS union ----------------
struct P1M { float ct[16][252]; int inv[4][16]; };
struct C2M { float ct[32][126]; };
struct C3M { float ct[64][49]; };
union SmemM { P1M p1; C2M c2; C3M c3; };

// ---------------------------------------------------------------------------
// mega256: 2304 blocks x 256 thr.
//  [0,1024)    perm1: MFMA conv1 (16 och, 7-row chunk) + upsample + perm
//  [1024,1536) conv2: MFMA (32 och, 7-row chunk) + upsample
//  [1536,1792) conv3: MFMA (64 och, full 7x7) + upsample
//  [1792,2304) conv4: MFMA GEMM (R7 verbatim)
// ---------------------------------------------------------------------------
__global__ void __launch_bounds__(256)
mega256(const unsigned short* __restrict__ f1T, const unsigned short* __restrict__ f2T,
        const unsigned short* __restrict__ f3T, const unsigned short* __restrict__ inT,
        const unsigned short* __restrict__ w1b, const unsigned short* __restrict__ w2b,
        const unsigned short* __restrict__ w3b, const unsigned short* __restrict__ w4b,
        const float* __restrict__ cb1, const float* __restrict__ cb2,
        const float* __restrict__ cb3, const float* __restrict__ cb4,
        const int* __restrict__ perms, float* __restrict__ out) {
  __shared__ SmemM sm;
  const int bid = blockIdx.x, tid = threadIdx.x;
  const int wave = tid >> 6, lane = tid & 63;
  const int l15 = lane & 15, lg = lane >> 4;
  float* o_aux1 = out + 32768;
  float* o_aux2 = o_aux1 + 12845056;
  float* o_aux3 = o_aux2 + 6422528;
  float* o_aux4 = o_aux3 + 3211264;

  if (bid < 1024) {
    // ================= perm1 =================
    const int b = bid >> 4, o0 = ((bid >> 2) & 3) * 16;
    const int r0 = (bid & 3) * 7, base = r0 - 1;

    if (tid >= 128 && tid < 192) {
      int t2 = tid - 128;
      int i = t2 >> 4, cl = t2 & 15;
      int c = o0 + cl;
      int r = 0;
      for (int j = 0; j < 64; ++j)
        if (perms[i * 64 + j] == c) r = j;
      sm.p1.inv[i][cl] = r;
    }

    // conv phase: wave = N-tile of 64 px (252 used of 256)
    const unsigned short* bp[4];
#pragma unroll
    for (int j = 0; j < 4; ++j) {
      int praw = wave * 64 + j * 16 + l15;
      int p = praw < 251 ? praw : 251;
      int lr = p / 28, x = p - lr * 28;
      int sr = base + lr;
      sr = sr < 0 ? 0 : (sr > 27 ? 27 : sr);
      bp[j] = f1T + ((size_t)b * 784 + sr * 28 + x) * 64 + lg * 8;
    }
    f32x4 acc[4];
    {
      float bv0 = cb1[o0 + lg * 4 + 0], bv1 = cb1[o0 + lg * 4 + 1];
      float bv2 = cb1[o0 + lg * 4 + 2], bv3 = cb1[o0 + lg * 4 + 3];
#pragma unroll
      for (int j = 0; j < 4; ++j) {
        acc[j][0] = bv0; acc[j][1] = bv1; acc[j][2] = bv2; acc[j][3] = bv3;
      }
    }
    const unsigned short* ap = w1b + (size_t)(o0 + l15) * 64 + lg * 8;
#pragma unroll
    for (int ks = 0; ks < 2; ++ks) {
      bf16x8 A = *(const bf16x8*)(ap + ks * 32);
#pragma unroll
      for (int j = 0; j < 4; ++j) {
        bf16x8 B = *(const bf16x8*)(bp[j] + ks * 32);
        acc[j] = __builtin_amdgcn_mfma_f32_16x16x32_bf16(A, B, acc[j], 0, 0, 0);
      }
    }
#pragma unroll
    for (int j = 0; j < 4; ++j) {
      int praw = wave * 64 + j * 16 + l15;
      if (praw < 252) {
#pragma unroll
        for (int r = 0; r < 4; ++r) sm.p1.ct[lg * 4 + r][praw] = acc[j][r];
      }
    }
    __syncthreads();

    // upsample + perm epilogue (R8 verbatim)
    const size_t obase = (size_t)b * 64 * 3136;
    for (int i = tid; i < 16 * 196; i += 256) {
      int cl = i / 196;
      int q = i - cl * 196;
      int ly = q / 28, qx = q - ly * 28;
      int qy = r0 + ly;
      int lr = ly + 1;
      int qi = ((qy >= 14) ? 2 : 0) + ((qx >= 14) ? 1 : 0);
      int j = sm.p1.inv[qi][cl];
      float* dst = o_aux1 + obase + (size_t)j * 3136 + (size_t)(2 * qy) * 56 + 2 * qx;
      up_quad_rows(&sm.p1.ct[cl][(lr - 1) * 28], &sm.p1.ct[cl][lr * 28],
                   &sm.p1.ct[cl][(lr + 1) * 28], qx, 28, dst, 56);
    }
  } else if (bid < 1536) {
    // ================= conv2 =================
    const int t = bid - 1024;
    const int b = t >> 3, o0 = ((t >> 1) & 3) * 32;
    const int r0 = (t & 1) * 7, base = r0 - 1;
    const int og = wave >> 1, nt = wave & 1;  // och half, N-tile
    const int om = o0 + og * 16;

    const unsigned short* bp[4];
#pragma unroll
    for (int j = 0; j < 4; ++j) {
      int praw = nt * 64 + j * 16 + l15;
      int p = praw < 125 ? praw : 125;
      int lr = p / 14, x = p - lr * 14;
      int sr = base + lr;
      sr = sr < 0 ? 0 : (sr > 13 ? 13 : sr);
      bp[j] = f2T + ((size_t)b * 196 + sr * 14 + x) * 128 + lg * 8;
    }
    f32x4 acc[4];
    {
      float bv0 = cb2[om + lg * 4 + 0], bv1 = cb2[om + lg * 4 + 1];
      float bv2 = cb2[om + lg * 4 + 2], bv3 = cb2[om + lg * 4 + 3];
#pragma unroll
      for (int j = 0; j < 4; ++j) {
        acc[j][0] = bv0; acc[j][1] = bv1; acc[j][2] = bv2; acc[j][3] = bv3;
      }
    }
    const unsigned short* ap = w2b + (size_t)(om + l15) * 128 + lg * 8;
#pragma unroll
    for (int ks = 0; ks < 4; ++ks) {
      bf16x8 A = *(const bf16x8*)(ap + ks * 32);
#pragma unroll
      for (int j = 0; j < 4; ++j) {
        bf16x8 B = *(const bf16x8*)(bp[j] + ks * 32);
        acc[j] = __builtin_amdgcn_mfma_f32_16x16x32_bf16(A, B, acc[j], 0, 0, 0);
      }
    }
#pragma unroll
    for (int j = 0; j < 4; ++j) {
      int praw = nt * 64 + j * 16 + l15;
      if (praw < 126) {
#pragma unroll
        for (int r = 0; r < 4; ++r) sm.c2.ct[og * 16 + lg * 4 + r][praw] = acc[j][r];
      }
    }
    __syncthreads();

    const size_t obase = (size_t)b * 128 * 784;
    for (int i = tid; i < 32 * 98; i += 256) {
      int cl = i / 98;
      int q = i - cl * 98;
      int ly = q / 14, qx = q - ly * 14;
      int qy = r0 + ly;
      int lr = ly + 1;
      float* dst = o_aux2 + obase + (size_t)(o0 + cl) * 784 + (size_t)(2 * qy) * 28 + 2 * qx;
      up_quad_rows(&sm.c2.ct[cl][(lr - 1) * 14], &sm.c2.ct[cl][lr * 14],
                   &sm.c2.ct[cl][(lr + 1) * 14], qx, 14, dst, 28);
    }
  } else if (bid < 1792) {
    // ================= conv3 =================
    const int t = bid - 1536;
    const int b = t >> 2, o0 = (t & 3) * 64;
    const int om = o0 + wave * 16;

    const unsigned short* bp[4];
#pragma unroll
    for (int j = 0; j < 4; ++j) {
      int p = j * 16 + l15;  // f3T zero-padded to 64 rows
      bp[j] = f3T + ((size_t)b * 64 + p) * 128 + lg * 8;
    }
    f32x4 acc[4];
    {
      float bv0 = cb3[om + lg * 4 + 0], bv1 = cb3[om + lg * 4 + 1];
      float bv2 = cb3[om + lg * 4 + 2], bv3 = cb3[om + lg * 4 + 3];
#pragma unroll
      for (int j = 0; j < 4; ++j) {
        acc[j][0] = bv0; acc[j][1] = bv1; acc[j][2] = bv2; acc[j][3] = bv3;
      }
    }
    const unsigned short* ap = w3b + (size_t)(om + l15) * 128 + lg * 8;
#pragma unroll
    for (int ks = 0; ks < 4; ++ks) {
      bf16x8 A = *(const bf16x8*)(ap + ks * 32);
#pragma unroll
      for (int j = 0; j < 4; ++j) {
        bf16x8 B = *(const bf16x8*)(bp[j] + ks * 32);
        acc[j] = __builtin_amdgcn_mfma_f32_16x16x32_bf16(A, B, acc[j], 0, 0, 0);
      }
    }
#pragma unroll
    for (int j = 0; j < 4; ++j) {
      int p = j * 16 + l15;
      if (p < 49) {
#pragma unroll
        for (int r = 0; r < 4; ++r) sm.c3.ct[wave * 16 + lg * 4 + r][p] = acc[j][r];
      }
    }
    __syncthreads();

    const size_t obase = (size_t)b * 256 * 196;
    for (int i = tid; i < 64 * 49; i += 256) {
      int cl = i / 49;
      int q = i - cl * 49;
      int qy = q / 7, qx = q - qy * 7;
      int rm = qy > 0 ? qy - 1 : 0, rp = qy < 6 ? qy + 1 : 6;
      float* dst = o_aux3 + obase + (size_t)(o0 + cl) * 196 + (size_t)(2 * qy) * 14 + 2 * qx;
      up_quad_rows(&sm.c3.ct[cl][rm * 7], &sm.c3.ct[cl][qy * 7], &sm.c3.ct[cl][rp * 7],
                   qx, 7, dst, 14);
    }
  } else {
    // ================= conv4 (R7 verbatim) =================
    const int t = bid - 1792;
    const int b = t >> 3;
    const int wm = (t & 7) * 64 + wave * 16;

    f32x4 acc[4];
    {
      float bv0 = cb4[wm + lg * 4 + 0];
      float bv1 = cb4[wm + lg * 4 + 1];
      float bv2 = cb4[wm + lg * 4 + 2];
      float bv3 = cb4[wm + lg * 4 + 3];
      for (int n = 0; n < 4; ++n) {
        acc[n][0] = bv0; acc[n][1] = bv1; acc[n][2] = bv2; acc[n][3] = bv3;
      }
    }

    const unsigned short* ap = w4b + (size_t)(wm + l15) * 512 + lg * 8;
    const unsigned short* bp = inT + (size_t)b * 64 * 512 + (size_t)l15 * 512 + lg * 8;

#pragma unroll 4
    for (int k0 = 0; k0 < 512; k0 += 32) {
      bf16x8 A  = *(const bf16x8*)(ap + k0);
      bf16x8 B0 = *(const bf16x8*)(bp + k0);
      bf16x8 B1 = *(const bf16x8*)(bp + 16 * 512 + k0);
      bf16x8 B2 = *(const bf16x8*)(bp + 32 * 512 + k0);
      bf16x8 B3 = *(const bf16x8*)(bp + 48 * 512 + k0);
      acc[0] = __builtin_amdgcn_mfma_f32_16x16x32_bf16(A, B0, acc[0], 0, 0, 0);
      acc[1] = __builtin_amdgcn_mfma_f32_16x16x32_bf16(A, B1, acc[1], 0, 0, 0);
      acc[2] = __builtin_amdgcn_mfma_f32_16x16x32_bf16(A, B2, acc[2], 0, 0, 0);
      acc[3] = __builtin_amdgcn_mfma_f32_16x16x32_bf16(A, B3, acc[3], 0, 0, 0);
    }

    float* outb = o_aux4 + (size_t)b * 512 * 49;
#pragma unroll
    for (int n = 0; n < 4; ++n) {
      int p = n * 16 + l15;
      if (p < 49) {
#pragma unroll
        for (int r = 0; r < 4; ++r) {
          int o = wm + lg * 4 + r;
          outb[(size_t)o * 49 + p] = acc[n][r];
        }
      }
    }
  }
}

extern "C" void kernel_launch(void* const* d_in, const int* in_sizes, int n_in,
                              void* d_out, int out_size, void* d_ws, size_t ws_size,
                              hipStream_t stream) {
  const float* f1      = (const float*)d_in[0];
  const float* f2      = (const float*)d_in[1];
  const float* f3      = (const float*)d_in[2];
  const float* f4      = (const float*)d_in[3];
  const float* x_final = (const float*)d_in[4];
  const float* cw1     = (const float*)d_in[5];
  const float* cb1     = (const float*)d_in[6];
  const float* cw2     = (const float*)d_in[7];
  const float* cb2     = (const float*)d_in[8];
  const float* cw3     = (const float*)d_in[9];
  const float* cb3     = (const float*)d_in[10];
  const float* cw4     = (const float*)d_in[11];
  const float* cb4     = (const float*)d_in[12];
  const float* w1      = (const float*)d_in[13];
  const float* w2      = (const float*)d_in[14];
  const float* w3      = (const float*)d_in[15];
  const float* w4      = (const float*)d_in[16];
  const int*   perms   = (const int*)d_in[17];

  float* out = (float*)d_out;

  unsigned short* ws  = (unsigned short*)d_ws;
  unsigned short* inT = ws;                      // 64*64*512      = 2,097,152
  unsigned short* f1T = inT + 2097152;           // 64*784*64      = 3,211,264
  unsigned short* f2T = f1T + 3211264;           // 64*196*128     = 1,605,632
  unsigned short* f3T = f2T + 1605632;           // 64*64*128      =   524,288
  unsigned short* w4b = f3T + 524288;            // 512*512        =   262,144
  unsigned short* w1b = w4b + 262144;            // 64*64          =     4,096
  unsigned short* w2b = w1b + 4096;              // 128*128        =    16,384
  unsigned short* w3b = w2b + 16384;             // 256*128        =    32,768

  setup256<<<768, 256, 0, stream>>>(f1, f2, f3, f4, cw1, cw2, cw3, cw4,
                                    x_final, w1, w2, w3, w4,
                                    f1T, f2T, f3T, inT, w1b, w2b, w3b, w4b, out);
  mega256<<<2304, 256, 0, stream>>>(f1T, f2T, f3T, inT, w1b, w2b, w3b, w4b,
                                    cb1, cb2, cb3, cb4, perms, out);
}